// Round 5
// baseline (1303.263 us; speedup 1.0000x reference)
//
#include <hip/hip_runtime.h>
#include <hip/hip_bf16.h>

#define N_NODES 163840
#define N_EDGES 2621440
#define NB      4096
#define NBUCK   320
#define BNODES  512
#define CAPB    9216

typedef __hip_bfloat16 bf16;
typedef __attribute__((ext_vector_type(8))) short short8;
typedef __attribute__((ext_vector_type(4))) float floatx4;

__device__ inline void storev(float* p, float v) { *p = v; }
__device__ inline void storev(bf16* p, float v) { *p = __float2bfloat16(v); }
__device__ inline float s2f(short s) {
  union { unsigned u; float f; } cv;
  cv.u = ((unsigned)(unsigned short)s) << 16;
  return cv.f;
}
__device__ inline short f2s(float f) {
  bf16 b = __float2bfloat16(f);
  return *(short*)&b;
}

// ======================= graph preprocessing (multisplit CSR) =======================
__global__ __launch_bounds__(256) void multisplit_kernel(
    const int* __restrict__ ei, int* __restrict__ gcur,
    int* __restrict__ ssrc, int* __restrict__ sdst) {
  __shared__ int hist[NBUCK];
  __shared__ int gbase[NBUCK];
  int tid = threadIdx.x;
  int base = blockIdx.x * 8192;
  for (int i = tid; i < NBUCK; i += 256) hist[i] = 0;
  __syncthreads();
  for (int r = 0; r < 32; r++) {
    int d = ei[N_EDGES + base + r * 256 + tid];
    atomicAdd(&hist[d >> 9], 1);
  }
  __syncthreads();
  for (int i = tid; i < NBUCK; i += 256) {
    int c = hist[i];
    gbase[i] = c ? atomicAdd(&gcur[i], c) : 0;
    hist[i] = 0;  // reuse as local cursor
  }
  __syncthreads();
  for (int r = 0; r < 32; r++) {
    int e = base + r * 256 + tid;
    int s = ei[e];
    int d = ei[N_EDGES + e];
    int bk = d >> 9;
    int pos = gbase[bk] + atomicAdd(&hist[bk], 1);
    sdst[pos] = d;
    ssrc[pos] = s;
  }
}

__global__ __launch_bounds__(256) void bucket_build_kernel(
    const int* __restrict__ ssrc, const int* __restrict__ sdst,
    const int* __restrict__ gcur, int* __restrict__ csr,
    int* __restrict__ rowstart, int* __restrict__ indeg,
    float* __restrict__ dinv) {
  int b = blockIdx.x;
  int lo = b * BNODES;
  int base = b * CAPB;
  int size = gcur[b] - base;
  __shared__ int hist[BNODES];
  __shared__ int part[128];
  int tid = threadIdx.x;
  for (int i = tid; i < BNODES; i += 256) hist[i] = 0;
  __syncthreads();
  for (int i = tid; i < size; i += 256)
    atomicAdd(&hist[sdst[base + i] - lo], 1);
  __syncthreads();
  int cnt4[4];
  if (tid < 128) {
    int s = 0;
    for (int j = 0; j < 4; j++) { cnt4[j] = hist[tid * 4 + j]; s += cnt4[j]; }
    part[tid] = s;
  }
  __syncthreads();
  for (int off = 1; off < 128; off <<= 1) {
    int v = 0;
    if (tid >= off && tid < 128) v = part[tid - off];
    __syncthreads();
    if (tid < 128) part[tid] += v;
    __syncthreads();
  }
  if (tid < 128) {
    int run = (tid == 0) ? 0 : part[tid - 1];
    for (int j = 0; j < 4; j++) {
      int i = tid * 4 + j;
      int c = cnt4[j];
      hist[i] = run;
      rowstart[lo + i] = base + run;
      indeg[lo + i] = c;
      dinv[lo + i] = rsqrtf((float)c + 1.0f);
      run += c;
    }
  }
  __syncthreads();
  for (int i = tid; i < size; i += 256) {
    int d = sdst[base + i];
    int pos = base + atomicAdd(&hist[d - lo], 1);
    csr[pos] = ssrc[base + i];
  }
}

// xb[n, 0:78] = x[n,:] * dinv[n]; cols 78..79 = 0  (padded [N,80], short8 stores)
__global__ __launch_bounds__(256) void cast_scale_kernel(const float* __restrict__ x,
                                                         const float* __restrict__ dinv,
                                                         bf16* __restrict__ xb) {
  int i = blockIdx.x * 256 + threadIdx.x;   // chunk id over N*10
  int n = i / 10, c = (i - n * 10) * 8;
  float dn = dinv[n];
  short8 pk;
#pragma unroll
  for (int j = 0; j < 8; j++) {
    int f = c + j;
    float v = (f < 78) ? x[(size_t)n * 78 + f] * dn : 0.f;
    pk[j] = f2s(v);
  }
  *(short8*)((short*)xb + (size_t)n * 80 + c) = pk;
}

// ======================= GCN aggregation (80-wide gather) ============
__global__ __launch_bounds__(256) void agg80_kernel(const bf16* __restrict__ hs,
                                                    const float* __restrict__ dinv,
                                                    const int* __restrict__ rowstart,
                                                    const int* __restrict__ indeg,
                                                    const int* __restrict__ csr,
                                                    bf16* __restrict__ out) {
  int node = blockIdx.x * 4 + (threadIdx.x >> 6);
  int lane = threadIdx.x & 63;
  int grp = lane / 10;          // 0..5 active, 6 idle
  int sub = lane - grp * 10;    // 0..9
  bool active = grp < 6;
  int st = rowstart[node];
  int deg = indeg[node];
  int en = st + deg;
  int cnt = deg + 1;            // edges + self
  float dn = dinv[node];
  int pre = (st + lane < en) ? csr[st + lane] : 0;
  float acc[8];
#pragma unroll
  for (int j = 0; j < 8; j++) acc[j] = 0.f;
  for (int e = 0; e < cnt; e += 6) {
    int ri = e + grp;
    bool valid = active && (ri < cnt);
    int idx = __shfl(pre, ri);
    if (ri >= 64) {
      int cidx = st + ri;
      cidx = (cidx < en) ? cidx : st;
      idx = csr[cidx];
    }
    int row = (active && ri < cnt - 1) ? idx : node;
    const short* rp = (const short*)hs + (size_t)row * 80 + sub * 8;
    short8 d = *(const short8*)rp;
    float m = valid ? 1.f : 0.f;
#pragma unroll
    for (int j = 0; j < 8; j++) acc[j] += m * s2f(d[j]);
  }
  short ob[8];
#pragma unroll
  for (int j = 0; j < 8; j++) {
    float v = acc[j];
    float t = 0.f;
#pragma unroll
    for (int g = 0; g < 6; g++) t += __shfl(v, sub + 10 * g);
    ob[j] = f2s(t * dn);
  }
  if (grp == 0) {
    short8 pk;
#pragma unroll
    for (int j = 0; j < 8; j++) pk[j] = ob[j];
    *(short8*)((short*)out + (size_t)node * 80 + sub * 8) = pk;
  }
}

// ========= fused layer-2 transform + relu + layer-3 aggregation (MFMA) =========
// out[n] = dinv[n]*( sum_src relu(ag2[src]@W2+b2)*dinv[src] + relu(ag2[n]@W2+b2)*dinv[n] )
// Gathers 80-wide ag2 rows (160 B) instead of 160-wide h2 (320 B): halves gather
// demand (839->420 MB) and removes the [N,160] h2 round-trip. Per node, rows come
// in batches of 16 (one per l16 lane), transformed via 16x16x32 MFMA with W2 in LDS
// (pad-88 stride: 2-way bank aliasing = free). relu+bias+dinv[src] applied per row
// in f32 BEFORE cross-row summation -> math identical to separate transform+gather.
__global__ __launch_bounds__(256) void gcn2t_agg3_kernel(
    const bf16* __restrict__ ag2, const float* __restrict__ dinv,
    const int* __restrict__ rowstart, const int* __restrict__ indeg,
    const int* __restrict__ csr, const bf16* __restrict__ Btw2,
    const float* __restrict__ b2, bf16* __restrict__ out) {
  __shared__ __align__(16) bf16 blds[160 * 88];   // W2^T [160 cols][80 k, pad 88]
  int tid = threadIdx.x;
  for (int i = tid; i < 160 * 80 / 8; i += 256) {
    int flat = i * 8;
    int col = flat / 80, k = flat - col * 80;
    *(short8*)&blds[col * 88 + k] = *(const short8*)((const short*)Btw2 + col * 96 + k);
  }
  int w = tid >> 6, lane = tid & 63;
  int quad = lane >> 4, l16 = lane & 15;
  int node = blockIdx.x * 4 + w;
  int st = rowstart[node];
  int deg = indeg[node];
  int en = st + deg;
  int cnt = deg + 1;
  float dn = dinv[node];
  int pre = (st + lane < en) ? csr[st + lane] : 0;
  float b2v[10];
#pragma unroll
  for (int nt = 0; nt < 10; nt++) {
    int c = nt * 16 + l16;
    b2v[nt] = (c < 156) ? b2[c] : 0.f;
  }
  floatx4 accf[10];
#pragma unroll
  for (int nt = 0; nt < 10; nt++) accf[nt] = (floatx4){0.f, 0.f, 0.f, 0.f};
  __syncthreads();
  const short8 zero8 = {0, 0, 0, 0, 0, 0, 0, 0};
  for (int b0 = 0; b0 < cnt; b0 += 16) {
    int ri = b0 + l16;
    int idx = __shfl(pre, ri);
    if (ri >= 64) {            // degree > 63: direct csr fallback (practically never)
      int cidx = st + ri;
      cidx = (cidx < en) ? cidx : st;
      idx = csr[cidx];
    }
    bool valid = ri < cnt;
    int row = (ri < cnt - 1) ? idx : node;
    float dl = valid ? dinv[row] : 0.f;   // 0 masks invalid rows (kills relu(b2) term)
    // A-frags: kstep s covers k = s*32 + quad*8
    const short* rp = (const short*)ag2 + (size_t)row * 80 + quad * 8;
    short8 a0 = *(const short8*)rp;
    short8 a1 = *(const short8*)(rp + 32);
    short8 a2 = (quad < 2) ? *(const short8*)(rp + 64) : zero8;
    float dr[4];
#pragma unroll
    for (int r = 0; r < 4; r++) dr[r] = __shfl(dl, quad * 4 + r);
#pragma unroll
    for (int nt = 0; nt < 10; nt++) {
      const short* bp = (const short*)&blds[(nt * 16 + l16) * 88 + quad * 8];
      short8 bb0 = *(const short8*)bp;
      short8 bb1 = *(const short8*)(bp + 32);
      short8 bb2 = (quad < 2) ? *(const short8*)(bp + 64) : zero8;
      floatx4 y = (floatx4){0.f, 0.f, 0.f, 0.f};
      y = __builtin_amdgcn_mfma_f32_16x16x32_bf16(a0, bb0, y, 0, 0, 0);
      y = __builtin_amdgcn_mfma_f32_16x16x32_bf16(a1, bb1, y, 0, 0, 0);
      y = __builtin_amdgcn_mfma_f32_16x16x32_bf16(a2, bb2, y, 0, 0, 0);
#pragma unroll
      for (int r = 0; r < 4; r++)
        accf[nt][r] += fmaxf(y[r] + b2v[nt], 0.f) * dr[r];
    }
  }
  // reduce the 16 C-rows -> column sums, scale by dn, store node row
#pragma unroll
  for (int nt = 0; nt < 10; nt++) {
    float s = accf[nt][0] + accf[nt][1] + accf[nt][2] + accf[nt][3];
    s += __shfl_xor(s, 16);
    s += __shfl_xor(s, 32);
    if (quad == 0)
      *((short*)out + (size_t)node * 160 + nt * 16 + l16) = f2s(s * dn);
  }
}

// ======================= MFMA GEMM (direct-register, no LDS) =======================
template <int NT, typename TC>
__global__ __launch_bounds__(256) void gemm_mfma_kernel(
    const bf16* __restrict__ A, const bf16* __restrict__ Bt,
    const float* __restrict__ bias, const float* __restrict__ rowScale,
    TC* __restrict__ C, int M, int Nc, int ncstore, int Ksteps, int lda,
    int kpad, int ldc, int coff, int doRelu) {
  int tid = threadIdx.x;
  int w = tid >> 6, lane = tid & 63;
  int quad = lane >> 4, l16 = lane & 15;
  int r0 = blockIdx.x * 64 + w * 16;
  int c0 = blockIdx.y * (NT * 16);
  floatx4 acc[NT];
#pragma unroll
  for (int t = 0; t < NT; t++) acc[t] = (floatx4){0.f, 0.f, 0.f, 0.f};
  const short* Ap = (const short*)A + (size_t)(r0 + l16) * lda + quad * 8;
  const short* Bp = (const short*)Bt + (size_t)(c0 + l16) * kpad + quad * 8;
  for (int s = 0; s < Ksteps; s++) {
    short8 a = *(const short8*)(Ap + s * 32);
#pragma unroll
    for (int t = 0; t < NT; t++) {
      short8 b = *(const short8*)(Bp + (size_t)t * 16 * kpad + s * 32);
      acc[t] = __builtin_amdgcn_mfma_f32_16x16x32_bf16(a, b, acc[t], 0, 0, 0);
    }
  }
#pragma unroll
  for (int t = 0; t < NT; t++) {
    int c = c0 + t * 16 + l16;
    if (c >= ncstore) continue;
    bool valid = c < Nc;
    float bb = (bias && valid) ? bias[c] : 0.f;
#pragma unroll
    for (int r = 0; r < 4; r++) {
      int row = r0 + quad * 4 + r;
      float v = valid ? acc[t][r] + bb : 0.f;
      if (doRelu) v = fmaxf(v, 0.f);
      if (rowScale) v *= rowScale[row];
      storev(&C[(size_t)row * ldc + coff + c], v);
    }
  }
}

// ================== merged weight prep (+ bucket cursor init) ==================
__device__ inline void wtrans_one(const float* __restrict__ W, bf16* __restrict__ Bt,
                                  int K, int N, int Kpad, int idx) {
  int n = idx / Kpad, k = idx - n * Kpad;
  float v = (k < K && n < N) ? W[(size_t)k * N + n] : 0.f;
  Bt[idx] = __float2bfloat16(v);
}
template <int CI, int NCO>
__device__ inline void wprep_one(const float* __restrict__ kw, bf16* __restrict__ Wr,
                                 int idx) {
  int co = idx % NCO, k = idx / NCO;
  int dl = k / CI, ci = k % CI;
  Wr[idx] = __float2bfloat16(kw[(co * CI + ci) * 8 + dl]);
}
__global__ __launch_bounds__(256) void wprep_all_kernel(
    const float* k2, const float* k3, const float* W1, const float* W2,
    const float* W3, const float* Wg1, const float* Wg2, const float* Wxt,
    const float* Wf1, const float* Wf2, bf16* Wr2, bf16* Wr3, bf16* Btw1,
    bf16* Btw2, bf16* BtW3, bf16* Btg1, bf16* Btg2, bf16* Btxt, bf16* Btf1,
    bf16* Btf2, int* gcur) {
  int idx = blockIdx.x * 256 + threadIdx.x;
  if (idx < 16384) { wprep_one<32, 64>(k2, Wr2, idx); return; }
  idx -= 16384;
  if (idx < 65536) { wprep_one<64, 128>(k3, Wr3, idx); return; }
  idx -= 65536;
  if (idx < 7680) { wtrans_one(W1, Btw1, 78, 78, 96, idx); return; }
  idx -= 7680;
  if (idx < 15360) { wtrans_one(W2, Btw2, 78, 156, 96, idx); return; }
  idx -= 15360;
  if (idx < 51200) { wtrans_one(W3, BtW3, 156, 312, 160, idx); return; }
  idx -= 51200;
  if (idx < 327680) { wtrans_one(Wg1, Btg1, 312, 1024, 320, idx); return; }
  idx -= 327680;
  if (idx < 131072) { wtrans_one(Wg2, Btg2, 1024, 128, 1024, idx); return; }
  idx -= 131072;
  if (idx < 376832) {  // Wxt permuted transpose
    int o = idx / 2944, k = idx - o * 2944;
    int l = k >> 7, co = k & 127;
    Btxt[idx] = __float2bfloat16(Wxt[((size_t)(co * 23 + l)) * 128 + o]);
    return;
  }
  idx -= 376832;
  if (idx < 262144) { wtrans_one(Wf1, Btf1, 256, 1024, 256, idx); return; }
  idx -= 262144;
  if (idx < 131072) { wtrans_one(Wf2, Btf2, 1024, 128, 1024, idx); return; }
  idx -= 131072;
  if (idx < NBUCK) gcur[idx] = idx * CAPB;
}
#define WPREP_TOTAL (16384 + 65536 + 7680 + 15360 + 51200 + 327680 + 131072 + 376832 + 262144 + 131072 + NBUCK)

// ======= fused layer-3 GCN transform + bias + relu + segment-max (MFMA) =============
__global__ __launch_bounds__(256) void gcn3_segmax_mfma_kernel(
    const bf16* __restrict__ agg2, const bf16* __restrict__ BtW3,
    const float* __restrict__ b3, bf16* __restrict__ g) {
  __shared__ __align__(16) bf16 a_lds[160 * 168];
  int tid = threadIdx.x;
  int w = tid >> 6, lane = tid & 63;
  int quad = lane >> 4, l16 = lane & 15;
  int g0 = blockIdx.x * 4;

  short8 bfrag[5][5];
  const short* Bp = (const short*)BtW3 + (size_t)(w * 80 + l16) * 160 + quad * 8;
#pragma unroll
  for (int nt = 0; nt < 5; nt++)
#pragma unroll
    for (int ks = 0; ks < 5; ks++)
      bfrag[nt][ks] = *(const short8*)(Bp + (size_t)nt * 16 * 160 + ks * 32);

  const bf16* src = agg2 + (size_t)g0 * 40 * 160;
  for (int i = tid; i < 160 * 160 / 8; i += 256) {
    int flat = i * 8;
    int row = flat / 160, k = flat - row * 160;
    *(short8*)&a_lds[row * 168 + k] = *(const short8*)&src[flat];
  }
  __syncthreads();

  float gmax[5][4];
#pragma unroll
  for (int nt = 0; nt < 5; nt++)
#pragma unroll
    for (int gi = 0; gi < 4; gi++) gmax[nt][gi] = -3.0e38f;

#pragma unroll
  for (int mt = 0; mt < 10; mt++) {
    floatx4 acc[5];
#pragma unroll
    for (int nt = 0; nt < 5; nt++) acc[nt] = (floatx4){0.f, 0.f, 0.f, 0.f};
#pragma unroll
    for (int ks = 0; ks < 5; ks++) {
      short8 a = *(const short8*)&a_lds[(16 * mt + l16) * 168 + ks * 32 + quad * 8];
#pragma unroll
      for (int nt = 0; nt < 5; nt++)
        acc[nt] = __builtin_amdgcn_mfma_f32_16x16x32_bf16(a, bfrag[nt][ks], acc[nt], 0, 0, 0);
    }
    int gl = (16 * mt + quad * 4) / 40;
#pragma unroll
    for (int nt = 0; nt < 5; nt++) {
      float m4 = fmaxf(fmaxf(acc[nt][0], acc[nt][1]), fmaxf(acc[nt][2], acc[nt][3]));
#pragma unroll
      for (int gi = 0; gi < 4; gi++)
        if (gl == gi) gmax[nt][gi] = fmaxf(gmax[nt][gi], m4);
    }
  }

#pragma unroll
  for (int nt = 0; nt < 5; nt++) {
#pragma unroll
    for (int gi = 0; gi < 4; gi++) {
      float v = gmax[nt][gi];
      v = fmaxf(v, __shfl_xor(v, 16));
      v = fmaxf(v, __shfl_xor(v, 32));
      gmax[nt][gi] = v;
    }
    int c = w * 80 + nt * 16 + l16;
    float bb = (c < 312) ? b3[c] : 0.f;
    float val = fmaxf(gmax[nt][quad] + bb, 0.f);
    g[(size_t)(g0 + quad) * 320 + c] = __float2bfloat16(val);
  }
}

// =========== fused conv1 + convA (implicit-GEMM, 3-tile-group pooling) ==============
// LDS: lds_in[248*40] bf16 (19840 B) + xin[735] f32 (2944 B) + stg[4][48][16] (6144 B)
#define CONV12_SMEM (248 * 40 * 2 + 2944 + 6144)
__global__ __launch_bounds__(256) void conv12_kernel(
    const float* __restrict__ xo, const float* __restrict__ k1,
    const float* __restrict__ kb1, const bf16* __restrict__ Wr2,
    const float* __restrict__ kb2, bf16* __restrict__ outp) {
  __shared__ __align__(16) char smem[CONV12_SMEM];
  bf16* lds_in = (bf16*)smem;
  float* xin = (float*)(smem + 248 * 40 * 2);
  bf16 (*stg)[48][16] = (bf16 (*)[48][16])(smem + 248 * 40 * 2 + 2944);
  int b = blockIdx.x;
  int tid = threadIdx.x;
  for (int i = tid; i < 735; i += 256) xin[i] = xo[(size_t)b * 735 + i];
  int co = tid & 31;
  float wreg[8];
#pragma unroll
  for (int k = 0; k < 8; k++) wreg[k] = k1[co * 8 + k];
  float bs = kb1[co];
  int w = tid >> 6, lane = tid & 63;
  int quad = lane >> 4, l16 = lane & 15;
  int co0 = w * 16;
  short8 bfrag[8];
#pragma unroll
  for (int s = 0; s < 8; s++)
#pragma unroll
    for (int j = 0; j < 8; j++)
      bfrag[s][j] = ((const short*)Wr2)[(s * 32 + quad * 8 + j) * 64 + co0 + l16];
  float biasv = kb2[co0 + l16];
  __syncthreads();  // xin ready
  // conv1 + relu-pool3 into lds_in (pos-major [242][40-padded])
  for (int idx = tid; idx < 242 * 32; idx += 256) {
    int l = idx >> 5;
    int base = l * 3;
    float a0 = bs, a1 = bs, a2 = bs;
#pragma unroll
    for (int k = 0; k < 8; k++) {
      float wv = wreg[k];
      a0 += wv * xin[base + k];
      a1 += wv * xin[base + 1 + k];
      a2 += wv * xin[base + 2 + k];
    }
    lds_in[l * 40 + co] =
        __float2bfloat16(fmaxf(0.f, fmaxf(a0, fmaxf(a1, a2))));
  }
  for (int idx = tid; idx < 6 * 32; idx += 256) {
    int rr = idx >> 5, cc = idx & 31;
    lds_in[(242 + rr) * 40 + cc] = __float2bfloat16(0.f);
  }
  __syncthreads();  // lds_in ready
  for (int t = 0; t < 5; t++) {
#pragma unroll
    for (int s3 = 0; s3 < 3; s3++) {
      int mt = 3 * t + s3;
      floatx4 acc = {0.f, 0.f, 0.f, 0.f};
      int m = mt * 16 + l16;
#pragma unroll
      for (int s = 0; s < 8; s++) {
        short8 a = *(const short8*)&lds_in[(m + s) * 40 + quad * 8];
        acc = __builtin_amdgcn_mfma_f32_16x16x32_bf16(a, bfrag[s], acc, 0, 0, 0);
      }
#pragma unroll
      for (int r = 0; r < 4; r++)
        stg[w][s3 * 16 + quad * 4 + r][l16] = __float2bfloat16(acc[r]);
    }
    // pool 48 rows -> 16 outputs (stg[w] is per-wave: no cross-wave barrier needed)
    for (int it = lane; it < 256; it += 64) {
      int lo = it >> 4;
      float v0 = __bfloat162float(stg[w][3 * lo][l16]);
      float v1 = __bfloat162float(stg[w][3 * lo + 1][l16]);
      float v2 = __bfloat162float(stg[w][3 * lo + 2][l16]);
      float v = fmaxf(fmaxf(v0, v1), v2) + biasv;
      int l = t * 16 + lo;
      if (l < 78)
        outp[((size_t)b * 78 + l) * 64 + co0 + l16] =
            __float2bfloat16(fmaxf(v, 0.f));
    }
  }
}

// ======================= MFMA implicit-GEMM conv + bias + relu + pool3 ==============
template <int CI, int LIN, int LPAD, int MT, int LOUT, int G, int NCO>
__global__ __launch_bounds__(256) void convmfma_kernel(const bf16* __restrict__ in,
                                                       const bf16* __restrict__ Wr,
                                                       const float* __restrict__ kb,
                                                       bf16* __restrict__ outp) {
  constexpr int KSTEPS = 8 * CI / 32;
  constexpr int CIP = CI + 8;
  __shared__ __align__(16) bf16 lds_in[G * LPAD * CIP];
  __shared__ bf16 stg[4][MT * 16][16];
  int tid = threadIdx.x;
  int w = tid >> 6, lane = tid & 63;
  int quad = lane >> 4, l16 = lane & 15;
  int bg = blockIdx.x;
  int co0 = blockIdx.y * 64 + w * 16;

  short8 bfrag[KSTEPS];
#pragma unroll
  for (int s = 0; s < KSTEPS; s++) {
#pragma unroll
    for (int j = 0; j < 8; j++) {
      int k = s * 32 + quad * 8 + j;
      bfrag[s][j] = ((const short*)Wr)[k * NCO + co0 + l16];
    }
  }

  const bf16* gin = in + (size_t)bg * G * LIN * CI;
  constexpr int NELEM = G * LIN * CI;
  for (int i = tid; i < NELEM / 8; i += 256) {
    int flat = i * 8;
    int g = flat / (LIN * CI);
    int rem = flat - g * (LIN * CI);
    int row = rem / CI, ci = rem - row * CI;
    *(short8*)&lds_in[(g * LPAD + row) * CIP + ci] = *(const short8*)&gin[flat];
  }
  constexpr int PADE = G * (LPAD - LIN) * CIP;
  for (int i = tid; i < PADE / 8; i += 256) {
    int flat = i * 8;
    int g = flat / ((LPAD - LIN) * CIP);
    int rem = flat - g * ((LPAD - LIN) * CIP);
    short8 z = {0, 0, 0, 0, 0, 0, 0, 0};
    *(short8*)&lds_in[(g * LPAD + LIN) * CIP + rem] = z;
  }
  __syncthreads();

  for (int g = 0; g < G; g++) {
    const bf16* base = &lds_in[g * LPAD * CIP];
#pragma unroll
    for (int mt = 0; mt < MT; mt++) {
      floatx4 acc = {0.f, 0.f, 0.f, 0.f};
      int m = mt * 16 + l16;
#pragma unroll
      for (int s = 0; s < KSTEPS; s++) {
        int kg0 = s * 32 + quad * 8;
        int dl = kg0 / CI;
        int ci0 = kg0 % CI;
        short8 a = *(const short8*)&base[(m + dl) * CIP + ci0];
        acc = __builtin_amdgcn_mfma_f32_16x16x32_bf16(a, bfrag[s], acc, 0, 0, 0);
      }
#pragma unroll
      for (int r = 0; r < 4; r++)
        stg[w][mt * 16 + quad * 4 + r][l16] = __float2bfloat16(acc[r]);
    }
    __syncthreads();
    float bias = kb[co0 + l16];
    for (int it = lane; it < LOUT * 16; it += 64) {
      int l = it >> 4;
      float v0 = __bfloat162float(stg[w][3 * l][l16]);
      float v1 = __bfloat162float(stg[w][3 * l + 1][l16]);
      float v2 = __bfloat162float(stg[w][3 * l + 2][l16]);
      float v = fmaxf(fmaxf(v0, v1), v2) + bias;
      outp[((size_t)(bg * G + g) * LOUT + l) * NCO + co0 + l16] =
          __float2bfloat16(fmaxf(v, 0.f));
    }
    __syncthreads();
  }
}

// ======================= final head =======================
__global__ __launch_bounds__(256) void final_kernel(const float* __restrict__ f2,
                                                    const float* __restrict__ Wo,
                                                    const float* __restrict__ bo,
                                                    float* __restrict__ out) {
  int wid = (blockIdx.x * blockDim.x + threadIdx.x) >> 6;
  int lane = threadIdx.x & 63;
  if (wid >= NB) return;
  float s = f2[wid * 128 + lane] * Wo[lane] + f2[wid * 128 + 64 + lane] * Wo[64 + lane];
  for (int o = 32; o > 0; o >>= 1) s += __shfl_down(s, o);
  if (lane == 0) out[wid] = s + bo[0];
}

// ======================= launch =======================
extern "C" void kernel_launch(void* const* d_in, const int* in_sizes, int n_in,
                              void* d_out, int out_size, void* d_ws, size_t ws_size,
                              hipStream_t stream) {
  const float* x   = (const float*)d_in[0];
  const int*   ei  = (const int*)d_in[1];
  const float* xo  = (const float*)d_in[3];
  const float* W1  = (const float*)d_in[4];  const float* b1  = (const float*)d_in[5];
  const float* W2  = (const float*)d_in[6];  const float* b2  = (const float*)d_in[7];
  const float* W3  = (const float*)d_in[8];  const float* b3  = (const float*)d_in[9];
  const float* Wg1 = (const float*)d_in[10]; const float* bg1 = (const float*)d_in[11];
  const float* Wg2 = (const float*)d_in[12]; const float* bg2 = (const float*)d_in[13];
  const float* k1  = (const float*)d_in[14]; const float* kb1 = (const float*)d_in[15];
  const float* k2  = (const float*)d_in[16]; const float* kb2 = (const float*)d_in[17];
  const float* k3  = (const float*)d_in[18]; const float* kb3 = (const float*)d_in[19];
  const float* Wxt = (const float*)d_in[20]; const float* bxt = (const float*)d_in[21];
  const float* Wf1 = (const float*)d_in[22]; const float* bf1 = (const float*)d_in[23];
  const float* Wf2 = (const float*)d_in[24]; const float* bf2 = (const float*)d_in[25];
  const float* Wo  = (const float*)d_in[26]; const float* bo  = (const float*)d_in[27];
  float* out = (float*)d_out;

  char* ws = (char*)d_ws;
  size_t off = 0;
  auto alloc = [&](size_t bytes) -> void* {
    void* p = ws + off;
    off += (bytes + 255) & ~(size_t)255;
    return p;
  };

  int*   indeg   = (int*)alloc((size_t)N_NODES * 4);
  float* dinv    = (float*)alloc((size_t)N_NODES * 4);
  int*   rowstart= (int*)alloc((size_t)N_NODES * 4);
  int*   gcur    = (int*)alloc(NBUCK * 4);
  int*   csr     = (int*)alloc((size_t)NBUCK * CAPB * 4 + 256);
  bf16*  nb1     = (bf16*)alloc((size_t)N_NODES * 160 * 2);
  bf16*  nb2     = (bf16*)alloc((size_t)NB * 7744 * 2);
  bf16*  gb      = (bf16*)alloc((size_t)NB * 320 * 2);
  bf16*  g1b     = (bf16*)alloc((size_t)NB * 1024 * 2);
  bf16*  gtb     = (bf16*)alloc((size_t)NB * 256 * 2);
  float* f2      = (float*)alloc((size_t)NB * 128 * 4);
  bf16*  Wr2     = (bf16*)alloc((size_t)256 * 64 * 2);
  bf16*  Wr3     = (bf16*)alloc((size_t)512 * 128 * 2);
  bf16*  Btw1    = (bf16*)alloc((size_t)80 * 96 * 2);
  bf16*  Btw2    = (bf16*)alloc((size_t)160 * 96 * 2);
  bf16*  BtW3    = (bf16*)alloc((size_t)320 * 160 * 2);
  bf16*  Btg1    = (bf16*)alloc((size_t)1024 * 320 * 2);
  bf16*  Btg2    = (bf16*)alloc((size_t)128 * 1024 * 2);
  bf16*  Btxt    = (bf16*)alloc((size_t)128 * 2944 * 2);
  bf16*  Btf1    = (bf16*)alloc((size_t)1024 * 256 * 2);
  bf16*  Btf2    = (bf16*)alloc((size_t)128 * 1024 * 2);

  // staging lives inside nb2 (dead until cast_scale runs)
  int* ssrc = (int*)nb2;
  int* sdst = ssrc + (size_t)NBUCK * CAPB;

  bf16* xb  = nb2;   // [N,80]
  bf16* h1  = nb2;   // [N,80] layer-1 output (over xb)
  bf16* ag  = nb1;   // agg buffers [N,80]
  bf16* ag3 = nb2;   // [N,160] fused layer-2T+agg3 output (over h1)
  bf16* c2  = nb1;   // [B,78,64] (over ag, dead after fused kernel)
  bf16* c3  = nb2;   // [B,23,128] flat [B,2944] (over ag3, dead after gcn3)
  bf16* f1b = g1b;

  // ---- weight prep + bucket cursor init (single launch) ----
  wprep_all_kernel<<<(WPREP_TOTAL + 255) / 256, 256, 0, stream>>>(
      k2, k3, W1, W2, W3, Wg1, Wg2, Wxt, Wf1, Wf2, Wr2, Wr3, Btw1, Btw2, BtW3,
      Btg1, Btg2, Btxt, Btf1, Btf2, gcur);

  // ---- CSR build (two-level multisplit) ----
  multisplit_kernel<<<NBUCK, 256, 0, stream>>>(ei, gcur, ssrc, sdst);
  bucket_build_kernel<<<NBUCK, 256, 0, stream>>>(ssrc, sdst, gcur, csr,
                                                 rowstart, indeg, dinv);

  // ---- GCN layers (aggregate-first; dinv folded into stored features) ----
  cast_scale_kernel<<<N_NODES * 10 / 256, 256, 0, stream>>>(x, dinv, xb);
  agg80_kernel<<<N_NODES / 4, 256, 0, stream>>>(xb, dinv, rowstart, indeg, csr, ag);
  gemm_mfma_kernel<5, bf16><<<dim3(N_NODES / 64, 1), 256, 0, stream>>>(
      ag, Btw1, b1, dinv, h1, N_NODES, 78, 80, 3, 80, 96, 80, 0, 1);
  agg80_kernel<<<N_NODES / 4, 256, 0, stream>>>(h1, dinv, rowstart, indeg, csr, ag);
  // fused layer-2 transform + relu + layer-3 aggregation (replaces gemm-l2 + agg160)
  gcn2t_agg3_kernel<<<N_NODES / 4, 256, 0, stream>>>(ag, dinv, rowstart, indeg,
                                                     csr, Btw2, b2, ag3);
  gcn3_segmax_mfma_kernel<<<NB / 4, 256, 0, stream>>>(ag3, BtW3, b3, gb);

  // ---- graph head (MFMA) ----
  gemm_mfma_kernel<4, bf16><<<dim3(NB / 64, 16), 256, 0, stream>>>(
      gb, Btg1, bg1, nullptr, g1b, NB, 1024, 1024, 10, 320, 320, 1024, 0, 1);
  gemm_mfma_kernel<4, bf16><<<dim3(NB / 64, 2), 256, 0, stream>>>(
      g1b, Btg2, bg2, nullptr, gtb, NB, 128, 128, 32, 1024, 1024, 256, 0, 0);

  // ---- conv tower (conv1 fused into convA; pos-major, MFMA) ----
  conv12_kernel<<<NB, 256, 0, stream>>>(xo, k1, kb1, Wr2, kb2, c2);
  convmfma_kernel<64, 78, 88, 5, 23, 4, 128>
      <<<dim3(NB / 4, 2), 256, 0, stream>>>(c2, Wr3, kb3, c3);
  gemm_mfma_kernel<4, bf16><<<dim3(NB / 64, 2), 256, 0, stream>>>(
      c3, Btxt, bxt, nullptr, gtb, NB, 128, 128, 92, 2944, 2944, 256, 128, 0);

  // ---- fused head (MFMA) ----
  gemm_mfma_kernel<4, bf16><<<dim3(NB / 64, 16), 256, 0, stream>>>(
      gtb, Btf1, bf1, nullptr, f1b, NB, 1024, 1024, 8, 256, 256, 1024, 0, 1);
  gemm_mfma_kernel<4, float><<<dim3(NB / 64, 2), 256, 0, stream>>>(
      f1b, Btf2, bf2, nullptr, f2, NB, 128, 128, 32, 1024, 1024, 128, 0, 1);
  final_kernel<<<NB * 64 / 256, 256, 0, stream>>>(f2, Wo, bo, out);
}

// Round 6
// 1030.846 us; speedup vs baseline: 1.2643x; 1.2643x over previous
//
#include <hip/hip_runtime.h>
#include <hip/hip_bf16.h>

#define N_NODES 163840
#define N_EDGES 2621440
#define NB      4096
#define NBUCK   320
#define BNODES  512
#define CAPB    9216

typedef __hip_bfloat16 bf16;
typedef __attribute__((ext_vector_type(8))) short short8;
typedef __attribute__((ext_vector_type(4))) float floatx4;

__device__ inline void storev(float* p, float v) { *p = v; }
__device__ inline void storev(bf16* p, float v) { *p = __float2bfloat16(v); }
__device__ inline float s2f(short s) {
  union { unsigned u; float f; } cv;
  cv.u = ((unsigned)(unsigned short)s) << 16;
  return cv.f;
}
__device__ inline short f2s(float f) {
  bf16 b = __float2bfloat16(f);
  return *(short*)&b;
}

// ======================= graph preprocessing (multisplit CSR) =======================
// Level 1: split edges into 320 buckets of 512 nodes. Near-full-line writes, no
// cross-XCD sharing of hot lines (fixes 14x WRITE amplification of naive scatter).
__global__ __launch_bounds__(256) void multisplit_kernel(
    const int* __restrict__ ei, int* __restrict__ gcur,
    int* __restrict__ ssrc, int* __restrict__ sdst) {
  __shared__ int hist[NBUCK];
  __shared__ int gbase[NBUCK];
  int tid = threadIdx.x;
  int base = blockIdx.x * 8192;
  for (int i = tid; i < NBUCK; i += 256) hist[i] = 0;
  __syncthreads();
  for (int r = 0; r < 32; r++) {
    int d = ei[N_EDGES + base + r * 256 + tid];
    atomicAdd(&hist[d >> 9], 1);
  }
  __syncthreads();
  for (int i = tid; i < NBUCK; i += 256) {
    int c = hist[i];
    gbase[i] = c ? atomicAdd(&gcur[i], c) : 0;
    hist[i] = 0;  // reuse as local cursor
  }
  __syncthreads();
  for (int r = 0; r < 32; r++) {
    int e = base + r * 256 + tid;
    int s = ei[e];
    int d = ei[N_EDGES + e];
    int bk = d >> 9;
    int pos = gbase[bk] + atomicAdd(&hist[bk], 1);
    sdst[pos] = d;
    ssrc[pos] = s;
  }
}

// Level 2: one wg per bucket builds rowstart/indeg/dinv + places csr (full lines,
// single XCD). Replaces count+scan1/2/3+scatter.
__global__ __launch_bounds__(256) void bucket_build_kernel(
    const int* __restrict__ ssrc, const int* __restrict__ sdst,
    const int* __restrict__ gcur, int* __restrict__ csr,
    int* __restrict__ rowstart, int* __restrict__ indeg,
    float* __restrict__ dinv) {
  int b = blockIdx.x;
  int lo = b * BNODES;
  int base = b * CAPB;
  int size = gcur[b] - base;
  __shared__ int hist[BNODES];
  __shared__ int part[128];
  int tid = threadIdx.x;
  for (int i = tid; i < BNODES; i += 256) hist[i] = 0;
  __syncthreads();
  for (int i = tid; i < size; i += 256)
    atomicAdd(&hist[sdst[base + i] - lo], 1);
  __syncthreads();
  int cnt4[4];
  if (tid < 128) {
    int s = 0;
    for (int j = 0; j < 4; j++) { cnt4[j] = hist[tid * 4 + j]; s += cnt4[j]; }
    part[tid] = s;
  }
  __syncthreads();
  for (int off = 1; off < 128; off <<= 1) {
    int v = 0;
    if (tid >= off && tid < 128) v = part[tid - off];
    __syncthreads();
    if (tid < 128) part[tid] += v;
    __syncthreads();
  }
  if (tid < 128) {
    int run = (tid == 0) ? 0 : part[tid - 1];
    for (int j = 0; j < 4; j++) {
      int i = tid * 4 + j;
      int c = cnt4[j];
      hist[i] = run;
      rowstart[lo + i] = base + run;
      indeg[lo + i] = c;
      dinv[lo + i] = rsqrtf((float)c + 1.0f);
      run += c;
    }
  }
  __syncthreads();
  for (int i = tid; i < size; i += 256) {
    int d = sdst[base + i];
    int pos = base + atomicAdd(&hist[d - lo], 1);
    csr[pos] = ssrc[base + i];
  }
}

// xb[n, 0:78] = x[n,:] * dinv[n]; cols 78..79 = 0  (padded [N,80], short8 stores)
__global__ __launch_bounds__(256) void cast_scale_kernel(const float* __restrict__ x,
                                                         const float* __restrict__ dinv,
                                                         bf16* __restrict__ xb) {
  int i = blockIdx.x * 256 + threadIdx.x;   // chunk id over N*10
  int n = i / 10, c = (i - n * 10) * 8;
  float dn = dinv[n];
  short8 pk;
#pragma unroll
  for (int j = 0; j < 8; j++) {
    int f = c + j;
    float v = (f < 78) ? x[(size_t)n * 78 + f] * dn : 0.f;
    pk[j] = f2s(v);
  }
  *(short8*)((short*)xb + (size_t)n * 80 + c) = pk;
}

// ======================= GCN aggregation (lean gather: 36 VGPR, 0 LDS) ============
// LAW (R2/R5 twice-confirmed): never attach MFMA/LDS compute to these kernels —
// they live on ~22 waves/CU of latency hiding and run at the ~3.8 TB/s random-64B
// service ceiling. Bytes cannot be bought with occupancy.

// F=80 (160 B rows, 10 chunks): 6 lane-groups x 10 chunks (lanes 60-63 idle).
__global__ __launch_bounds__(256) void agg80_kernel(const bf16* __restrict__ hs,
                                                    const float* __restrict__ dinv,
                                                    const int* __restrict__ rowstart,
                                                    const int* __restrict__ indeg,
                                                    const int* __restrict__ csr,
                                                    bf16* __restrict__ out) {
  int node = blockIdx.x * 4 + (threadIdx.x >> 6);
  int lane = threadIdx.x & 63;
  int grp = lane / 10;          // 0..5 active, 6 idle
  int sub = lane - grp * 10;    // 0..9
  bool active = grp < 6;
  int st = rowstart[node];
  int deg = indeg[node];
  int en = st + deg;
  int cnt = deg + 1;            // edges + self
  float dn = dinv[node];
  int pre = (st + lane < en) ? csr[st + lane] : 0;
  float acc[8];
#pragma unroll
  for (int j = 0; j < 8; j++) acc[j] = 0.f;
  for (int e = 0; e < cnt; e += 6) {
    int ri = e + grp;
    bool valid = active && (ri < cnt);
    int idx = __shfl(pre, ri);
    if (ri >= 64) {
      int cidx = st + ri;
      cidx = (cidx < en) ? cidx : st;
      idx = csr[cidx];
    }
    int row = (active && ri < cnt - 1) ? idx : node;
    const short* rp = (const short*)hs + (size_t)row * 80 + sub * 8;
    short8 d = *(const short8*)rp;
    float m = valid ? 1.f : 0.f;
#pragma unroll
    for (int j = 0; j < 8; j++) acc[j] += m * s2f(d[j]);
  }
  short ob[8];
#pragma unroll
  for (int j = 0; j < 8; j++) {
    float v = acc[j];
    float t = 0.f;
#pragma unroll
    for (int g = 0; g < 6; g++) t += __shfl(v, sub + 10 * g);
    ob[j] = f2s(t * dn);
  }
  if (grp == 0) {
    short8 pk;
#pragma unroll
    for (int j = 0; j < 8; j++) pk[j] = ob[j];
    *(short8*)((short*)out + (size_t)node * 80 + sub * 8) = pk;
  }
}

// F=160 gather (320 B rows = 5 aligned 64B lines), writes 160-wide.
__global__ __launch_bounds__(256) void agg160_kernel(const bf16* __restrict__ hs,
                                                     const float* __restrict__ dinv,
                                                     const int* __restrict__ rowstart,
                                                     const int* __restrict__ indeg,
                                                     const int* __restrict__ csr,
                                                     bf16* __restrict__ out) {
  int node = blockIdx.x * 4 + (threadIdx.x >> 6);
  int lane = threadIdx.x & 63;
  int grp = lane >> 3;          // 0..7
  int sub = lane & 7;           // 0..7
  int st = rowstart[node];
  int deg = indeg[node];
  int en = st + deg;
  int cnt = deg + 1;
  float dn = dinv[node];
  int pre = (st + lane < en) ? csr[st + lane] : 0;
  float acc0[8], acc1[8], acc2[8];
#pragma unroll
  for (int j = 0; j < 8; j++) { acc0[j] = 0.f; acc1[j] = 0.f; acc2[j] = 0.f; }
  for (int e = 0; e < cnt; e += 8) {
    int ri = e + grp;
    bool valid = ri < cnt;
    int idx = __shfl(pre, ri);
    if (ri >= 64) {
      int cidx = st + ri;
      cidx = (cidx < en) ? cidx : st;
      idx = csr[cidx];
    }
    int row = (ri < cnt - 1) ? idx : node;
    const short* rp = (const short*)hs + (size_t)row * 160 + sub * 8;
    short8 d0 = *(const short8*)rp;
    short8 d1 = *(const short8*)(rp + 64);
    short8 d2 = *(const short8*)(rp + (sub < 4 ? 128 : 0));
    float m = valid ? 1.f : 0.f;
    float m2 = (valid && sub < 4) ? 1.f : 0.f;
#pragma unroll
    for (int j = 0; j < 8; j++) {
      acc0[j] += m * s2f(d0[j]);
      acc1[j] += m * s2f(d1[j]);
      acc2[j] += m2 * s2f(d2[j]);
    }
  }
  {
    short8 pk;
#pragma unroll
    for (int j = 0; j < 8; j++) {
      float v = acc0[j];
      v += __shfl_xor(v, 8); v += __shfl_xor(v, 16); v += __shfl_xor(v, 32);
      pk[j] = f2s(v * dn);
    }
    if (grp == 0) *(short8*)((short*)out + (size_t)node * 160 + sub * 8) = pk;
  }
  {
    short8 pk;
#pragma unroll
    for (int j = 0; j < 8; j++) {
      float v = acc1[j];
      v += __shfl_xor(v, 8); v += __shfl_xor(v, 16); v += __shfl_xor(v, 32);
      pk[j] = f2s(v * dn);
    }
    if (grp == 0) *(short8*)((short*)out + (size_t)node * 160 + 64 + sub * 8) = pk;
  }
  {
    short8 pk;
#pragma unroll
    for (int j = 0; j < 8; j++) {
      float v = acc2[j];
      v += __shfl_xor(v, 8); v += __shfl_xor(v, 16); v += __shfl_xor(v, 32);
      pk[j] = f2s(v * dn);
    }
    if (grp == 0 && sub < 4)
      *(short8*)((short*)out + (size_t)node * 160 + 128 + sub * 8) = pk;
  }
}

// ======================= MFMA GEMM (direct-register, no LDS) =======================
template <int NT, typename TC>
__global__ __launch_bounds__(256) void gemm_mfma_kernel(
    const bf16* __restrict__ A, const bf16* __restrict__ Bt,
    const float* __restrict__ bias, const float* __restrict__ rowScale,
    TC* __restrict__ C, int M, int Nc, int ncstore, int Ksteps, int lda,
    int kpad, int ldc, int coff, int doRelu) {
  int tid = threadIdx.x;
  int w = tid >> 6, lane = tid & 63;
  int quad = lane >> 4, l16 = lane & 15;
  int r0 = blockIdx.x * 64 + w * 16;
  int c0 = blockIdx.y * (NT * 16);
  floatx4 acc[NT];
#pragma unroll
  for (int t = 0; t < NT; t++) acc[t] = (floatx4){0.f, 0.f, 0.f, 0.f};
  const short* Ap = (const short*)A + (size_t)(r0 + l16) * lda + quad * 8;
  const short* Bp = (const short*)Bt + (size_t)(c0 + l16) * kpad + quad * 8;
  for (int s = 0; s < Ksteps; s++) {
    short8 a = *(const short8*)(Ap + s * 32);
#pragma unroll
    for (int t = 0; t < NT; t++) {
      short8 b = *(const short8*)(Bp + (size_t)t * 16 * kpad + s * 32);
      acc[t] = __builtin_amdgcn_mfma_f32_16x16x32_bf16(a, b, acc[t], 0, 0, 0);
    }
  }
#pragma unroll
  for (int t = 0; t < NT; t++) {
    int c = c0 + t * 16 + l16;
    if (c >= ncstore) continue;
    bool valid = c < Nc;
    float bb = (bias && valid) ? bias[c] : 0.f;
#pragma unroll
    for (int r = 0; r < 4; r++) {
      int row = r0 + quad * 4 + r;
      float v = valid ? acc[t][r] + bb : 0.f;
      if (doRelu) v = fmaxf(v, 0.f);
      if (rowScale) v *= rowScale[row];
      storev(&C[(size_t)row * ldc + coff + c], v);
    }
  }
}

// ================== merged weight prep (+ bucket cursor init) ==================
__device__ inline void wtrans_one(const float* __restrict__ W, bf16* __restrict__ Bt,
                                  int K, int N, int Kpad, int idx) {
  int n = idx / Kpad, k = idx - n * Kpad;
  float v = (k < K && n < N) ? W[(size_t)k * N + n] : 0.f;
  Bt[idx] = __float2bfloat16(v);
}
template <int CI, int NCO>
__device__ inline void wprep_one(const float* __restrict__ kw, bf16* __restrict__ Wr,
                                 int idx) {
  int co = idx % NCO, k = idx / NCO;
  int dl = k / CI, ci = k % CI;
  Wr[idx] = __float2bfloat16(kw[(co * CI + ci) * 8 + dl]);
}
__global__ __launch_bounds__(256) void wprep_all_kernel(
    const float* k2, const float* k3, const float* W1, const float* W2,
    const float* W3, const float* Wg1, const float* Wg2, const float* Wxt,
    const float* Wf1, const float* Wf2, bf16* Wr2, bf16* Wr3, bf16* Btw1,
    bf16* Btw2, bf16* BtW3, bf16* Btg1, bf16* Btg2, bf16* Btxt, bf16* Btf1,
    bf16* Btf2, int* gcur) {
  int idx = blockIdx.x * 256 + threadIdx.x;
  if (idx < 16384) { wprep_one<32, 64>(k2, Wr2, idx); return; }
  idx -= 16384;
  if (idx < 65536) { wprep_one<64, 128>(k3, Wr3, idx); return; }
  idx -= 65536;
  if (idx < 7680) { wtrans_one(W1, Btw1, 78, 78, 96, idx); return; }
  idx -= 7680;
  if (idx < 15360) { wtrans_one(W2, Btw2, 78, 156, 96, idx); return; }
  idx -= 15360;
  if (idx < 51200) { wtrans_one(W3, BtW3, 156, 312, 160, idx); return; }
  idx -= 51200;
  if (idx < 327680) { wtrans_one(Wg1, Btg1, 312, 1024, 320, idx); return; }
  idx -= 327680;
  if (idx < 131072) { wtrans_one(Wg2, Btg2, 1024, 128, 1024, idx); return; }
  idx -= 131072;
  if (idx < 376832) {  // Wxt permuted transpose
    int o = idx / 2944, k = idx - o * 2944;
    int l = k >> 7, co = k & 127;
    Btxt[idx] = __float2bfloat16(Wxt[((size_t)(co * 23 + l)) * 128 + o]);
    return;
  }
  idx -= 376832;
  if (idx < 262144) { wtrans_one(Wf1, Btf1, 256, 1024, 256, idx); return; }
  idx -= 262144;
  if (idx < 131072) { wtrans_one(Wf2, Btf2, 1024, 128, 1024, idx); return; }
  idx -= 131072;
  if (idx < NBUCK) gcur[idx] = idx * CAPB;
}
#define WPREP_TOTAL (16384 + 65536 + 7680 + 15360 + 51200 + 327680 + 131072 + 376832 + 262144 + 131072 + NBUCK)

// ======= fused layer-3 GCN transform + bias + relu + segment-max (MFMA) =============
__global__ __launch_bounds__(256) void gcn3_segmax_mfma_kernel(
    const bf16* __restrict__ agg2, const bf16* __restrict__ BtW3,
    const float* __restrict__ b3, bf16* __restrict__ g) {
  __shared__ __align__(16) bf16 a_lds[160 * 168];
  int tid = threadIdx.x;
  int w = tid >> 6, lane = tid & 63;
  int quad = lane >> 4, l16 = lane & 15;
  int g0 = blockIdx.x * 4;

  short8 bfrag[5][5];
  const short* Bp = (const short*)BtW3 + (size_t)(w * 80 + l16) * 160 + quad * 8;
#pragma unroll
  for (int nt = 0; nt < 5; nt++)
#pragma unroll
    for (int ks = 0; ks < 5; ks++)
      bfrag[nt][ks] = *(const short8*)(Bp + (size_t)nt * 16 * 160 + ks * 32);

  const bf16* src = agg2 + (size_t)g0 * 40 * 160;
  for (int i = tid; i < 160 * 160 / 8; i += 256) {
    int flat = i * 8;
    int row = flat / 160, k = flat - row * 160;
    *(short8*)&a_lds[row * 168 + k] = *(const short8*)&src[flat];
  }
  __syncthreads();

  float gmax[5][4];
#pragma unroll
  for (int nt = 0; nt < 5; nt++)
#pragma unroll
    for (int gi = 0; gi < 4; gi++) gmax[nt][gi] = -3.0e38f;

#pragma unroll
  for (int mt = 0; mt < 10; mt++) {
    floatx4 acc[5];
#pragma unroll
    for (int nt = 0; nt < 5; nt++) acc[nt] = (floatx4){0.f, 0.f, 0.f, 0.f};
#pragma unroll
    for (int ks = 0; ks < 5; ks++) {
      short8 a = *(const short8*)&a_lds[(16 * mt + l16) * 168 + ks * 32 + quad * 8];
#pragma unroll
      for (int nt = 0; nt < 5; nt++)
        acc[nt] = __builtin_amdgcn_mfma_f32_16x16x32_bf16(a, bfrag[nt][ks], acc[nt], 0, 0, 0);
    }
    int gl = (16 * mt + quad * 4) / 40;
#pragma unroll
    for (int nt = 0; nt < 5; nt++) {
      float m4 = fmaxf(fmaxf(acc[nt][0], acc[nt][1]), fmaxf(acc[nt][2], acc[nt][3]));
#pragma unroll
      for (int gi = 0; gi < 4; gi++)
        if (gl == gi) gmax[nt][gi] = fmaxf(gmax[nt][gi], m4);
    }
  }

#pragma unroll
  for (int nt = 0; nt < 5; nt++) {
#pragma unroll
    for (int gi = 0; gi < 4; gi++) {
      float v = gmax[nt][gi];
      v = fmaxf(v, __shfl_xor(v, 16));
      v = fmaxf(v, __shfl_xor(v, 32));
      gmax[nt][gi] = v;
    }
    int c = w * 80 + nt * 16 + l16;
    float bb = (c < 312) ? b3[c] : 0.f;
    float val = fmaxf(gmax[nt][quad] + bb, 0.f);
    g[(size_t)(g0 + quad) * 320 + c] = __float2bfloat16(val);
  }
}

// =========== fused conv1 + convA (implicit-GEMM, 3-tile-group pooling) ==============
// Eliminates the c1 [B,242,32] 63 MB round-trip + one launch (verified R5).
// LDS: lds_in[248*40] bf16 (19840 B) + xin[735] f32 (2944 B) + stg[4][48][16] (6144 B)
#define CONV12_SMEM (248 * 40 * 2 + 2944 + 6144)
__global__ __launch_bounds__(256) void conv12_kernel(
    const float* __restrict__ xo, const float* __restrict__ k1,
    const float* __restrict__ kb1, const bf16* __restrict__ Wr2,
    const float* __restrict__ kb2, bf16* __restrict__ outp) {
  __shared__ __align__(16) char smem[CONV12_SMEM];
  bf16* lds_in = (bf16*)smem;
  float* xin = (float*)(smem + 248 * 40 * 2);
  bf16 (*stg)[48][16] = (bf16 (*)[48][16])(smem + 248 * 40 * 2 + 2944);
  int b = blockIdx.x;
  int tid = threadIdx.x;
  for (int i = tid; i < 735; i += 256) xin[i] = xo[(size_t)b * 735 + i];
  int co = tid & 31;
  float wreg[8];
#pragma unroll
  for (int k = 0; k < 8; k++) wreg[k] = k1[co * 8 + k];
  float bs = kb1[co];
  int w = tid >> 6, lane = tid & 63;
  int quad = lane >> 4, l16 = lane & 15;
  int co0 = w * 16;
  short8 bfrag[8];
#pragma unroll
  for (int s = 0; s < 8; s++)
#pragma unroll
    for (int j = 0; j < 8; j++)
      bfrag[s][j] = ((const short*)Wr2)[(s * 32 + quad * 8 + j) * 64 + co0 + l16];
  float biasv = kb2[co0 + l16];
  __syncthreads();  // xin ready
  // conv1 + relu-pool3 into lds_in (pos-major [242][40-padded])
  for (int idx = tid; idx < 242 * 32; idx += 256) {
    int l = idx >> 5;
    int base = l * 3;
    float a0 = bs, a1 = bs, a2 = bs;
#pragma unroll
    for (int k = 0; k < 8; k++) {
      float wv = wreg[k];
      a0 += wv * xin[base + k];
      a1 += wv * xin[base + 1 + k];
      a2 += wv * xin[base + 2 + k];
    }
    lds_in[l * 40 + co] =
        __float2bfloat16(fmaxf(0.f, fmaxf(a0, fmaxf(a1, a2))));
  }
  for (int idx = tid; idx < 6 * 32; idx += 256) {
    int rr = idx >> 5, cc = idx & 31;
    lds_in[(242 + rr) * 40 + cc] = __float2bfloat16(0.f);
  }
  __syncthreads();  // lds_in ready
  for (int t = 0; t < 5; t++) {
#pragma unroll
    for (int s3 = 0; s3 < 3; s3++) {
      int mt = 3 * t + s3;
      floatx4 acc = {0.f, 0.f, 0.f, 0.f};
      int m = mt * 16 + l16;
#pragma unroll
      for (int s = 0; s < 8; s++) {
        short8 a = *(const short8*)&lds_in[(m + s) * 40 + quad * 8];
        acc = __builtin_amdgcn_mfma_f32_16x16x32_bf16(a, bfrag[s], acc, 0, 0, 0);
      }
#pragma unroll
      for (int r = 0; r < 4; r++)
        stg[w][s3 * 16 + quad * 4 + r][l16] = __float2bfloat16(acc[r]);
    }
    // pool 48 rows -> 16 outputs (stg[w] is per-wave: no cross-wave barrier needed)
    for (int it = lane; it < 256; it += 64) {
      int lo = it >> 4;
      float v0 = __bfloat162float(stg[w][3 * lo][l16]);
      float v1 = __bfloat162float(stg[w][3 * lo + 1][l16]);
      float v2 = __bfloat162float(stg[w][3 * lo + 2][l16]);
      float v = fmaxf(fmaxf(v0, v1), v2) + biasv;
      int l = t * 16 + lo;
      if (l < 78)
        outp[((size_t)b * 78 + l) * 64 + co0 + l16] =
            __float2bfloat16(fmaxf(v, 0.f));
    }
  }
}

// ======================= MFMA implicit-GEMM conv + bias + relu + pool3 ==============
template <int CI, int LIN, int LPAD, int MT, int LOUT, int G, int NCO>
__global__ __launch_bounds__(256) void convmfma_kernel(const bf16* __restrict__ in,
                                                       const bf16* __restrict__ Wr,
                                                       const float* __restrict__ kb,
                                                       bf16* __restrict__ outp) {
  constexpr int KSTEPS = 8 * CI / 32;
  constexpr int CIP = CI + 8;
  __shared__ __align__(16) bf16 lds_in[G * LPAD * CIP];
  __shared__ bf16 stg[4][MT * 16][16];
  int tid = threadIdx.x;
  int w = tid >> 6, lane = tid & 63;
  int quad = lane >> 4, l16 = lane & 15;
  int bg = blockIdx.x;
  int co0 = blockIdx.y * 64 + w * 16;

  short8 bfrag[KSTEPS];
#pragma unroll
  for (int s = 0; s < KSTEPS; s++) {
#pragma unroll
    for (int j = 0; j < 8; j++) {
      int k = s * 32 + quad * 8 + j;
      bfrag[s][j] = ((const short*)Wr)[k * NCO + co0 + l16];
    }
  }

  const bf16* gin = in + (size_t)bg * G * LIN * CI;
  constexpr int NELEM = G * LIN * CI;
  for (int i = tid; i < NELEM / 8; i += 256) {
    int flat = i * 8;
    int g = flat / (LIN * CI);
    int rem = flat - g * (LIN * CI);
    int row = rem / CI, ci = rem - row * CI;
    *(short8*)&lds_in[(g * LPAD + row) * CIP + ci] = *(const short8*)&gin[flat];
  }
  constexpr int PADE = G * (LPAD - LIN) * CIP;
  for (int i = tid; i < PADE / 8; i += 256) {
    int flat = i * 8;
    int g = flat / ((LPAD - LIN) * CIP);
    int rem = flat - g * ((LPAD - LIN) * CIP);
    short8 z = {0, 0, 0, 0, 0, 0, 0, 0};
    *(short8*)&lds_in[(g * LPAD + LIN) * CIP + rem] = z;
  }
  __syncthreads();

  for (int g = 0; g < G; g++) {
    const bf16* base = &lds_in[g * LPAD * CIP];
#pragma unroll
    for (int mt = 0; mt < MT; mt++) {
      floatx4 acc = {0.f, 0.f, 0.f, 0.f};
      int m = mt * 16 + l16;
#pragma unroll
      for (int s = 0; s < KSTEPS; s++) {
        int kg0 = s * 32 + quad * 8;
        int dl = kg0 / CI;
        int ci0 = kg0 % CI;
        short8 a = *(const short8*)&base[(m + dl) * CIP + ci0];
        acc = __builtin_amdgcn_mfma_f32_16x16x32_bf16(a, bfrag[s], acc, 0, 0, 0);
      }
#pragma unroll
      for (int r = 0; r < 4; r++)
        stg[w][mt * 16 + quad * 4 + r][l16] = __float2bfloat16(acc[r]);
    }
    __syncthreads();
    float bias = kb[co0 + l16];
    for (int it = lane; it < LOUT * 16; it += 64) {
      int l = it >> 4;
      float v0 = __bfloat162float(stg[w][3 * l][l16]);
      float v1 = __bfloat162float(stg[w][3 * l + 1][l16]);
      float v2 = __bfloat162float(stg[w][3 * l + 2][l16]);
      float v = fmaxf(fmaxf(v0, v1), v2) + bias;
      outp[((size_t)(bg * G + g) * LOUT + l) * NCO + co0 + l16] =
          __float2bfloat16(fmaxf(v, 0.f));
    }
    __syncthreads();
  }
}

// ======================= final head =======================
__global__ __launch_bounds__(256) void final_kernel(const float* __restrict__ f2,
                                                    const float* __restrict__ Wo,
                                                    const float* __restrict__ bo,
                                                    float* __restrict__ out) {
  int wid = (blockIdx.x * blockDim.x + threadIdx.x) >> 6;
  int lane = threadIdx.x & 63;
  if (wid >= NB) return;
  float s = f2[wid * 128 + lane] * Wo[lane] + f2[wid * 128 + 64 + lane] * Wo[64 + lane];
  for (int o = 32; o > 0; o >>= 1) s += __shfl_down(s, o);
  if (lane == 0) out[wid] = s + bo[0];
}

// ======================= launch =======================
extern "C" void kernel_launch(void* const* d_in, const int* in_sizes, int n_in,
                              void* d_out, int out_size, void* d_ws, size_t ws_size,
                              hipStream_t stream) {
  const float* x   = (const float*)d_in[0];
  const int*   ei  = (const int*)d_in[1];
  const float* xo  = (const float*)d_in[3];
  const float* W1  = (const float*)d_in[4];  const float* b1  = (const float*)d_in[5];
  const float* W2  = (const float*)d_in[6];  const float* b2  = (const float*)d_in[7];
  const float* W3  = (const float*)d_in[8];  const float* b3  = (const float*)d_in[9];
  const float* Wg1 = (const float*)d_in[10]; const float* bg1 = (const float*)d_in[11];
  const float* Wg2 = (const float*)d_in[12]; const float* bg2 = (const float*)d_in[13];
  const float* k1  = (const float*)d_in[14]; const float* kb1 = (const float*)d_in[15];
  const float* k2  = (const float*)d_in[16]; const float* kb2 = (const float*)d_in[17];
  const float* k3  = (const float*)d_in[18]; const float* kb3 = (const float*)d_in[19];
  const float* Wxt = (const float*)d_in[20]; const float* bxt = (const float*)d_in[21];
  const float* Wf1 = (const float*)d_in[22]; const float* bf1 = (const float*)d_in[23];
  const float* Wf2 = (const float*)d_in[24]; const float* bf2 = (const float*)d_in[25];
  const float* Wo  = (const float*)d_in[26]; const float* bo  = (const float*)d_in[27];
  float* out = (float*)d_out;

  char* ws = (char*)d_ws;
  size_t off = 0;
  auto alloc = [&](size_t bytes) -> void* {
    void* p = ws + off;
    off += (bytes + 255) & ~(size_t)255;
    return p;
  };

  int*   indeg   = (int*)alloc((size_t)N_NODES * 4);
  float* dinv    = (float*)alloc((size_t)N_NODES * 4);
  int*   rowstart= (int*)alloc((size_t)N_NODES * 4);
  int*   gcur    = (int*)alloc(NBUCK * 4);
  int*   csr     = (int*)alloc((size_t)NBUCK * CAPB * 4 + 256);
  bf16*  nb1     = (bf16*)alloc((size_t)N_NODES * 160 * 2);
  bf16*  nb2     = (bf16*)alloc((size_t)NB * 7744 * 2);
  bf16*  gb      = (bf16*)alloc((size_t)NB * 320 * 2);
  bf16*  g1b     = (bf16*)alloc((size_t)NB * 1024 * 2);
  bf16*  gtb     = (bf16*)alloc((size_t)NB * 256 * 2);
  float* f2      = (float*)alloc((size_t)NB * 128 * 4);
  bf16*  Wr2     = (bf16*)alloc((size_t)256 * 64 * 2);
  bf16*  Wr3     = (bf16*)alloc((size_t)512 * 128 * 2);
  bf16*  Btw1    = (bf16*)alloc((size_t)80 * 96 * 2);
  bf16*  Btw2    = (bf16*)alloc((size_t)160 * 96 * 2);
  bf16*  BtW3    = (bf16*)alloc((size_t)320 * 160 * 2);
  bf16*  Btg1    = (bf16*)alloc((size_t)1024 * 320 * 2);
  bf16*  Btg2    = (bf16*)alloc((size_t)128 * 1024 * 2);
  bf16*  Btxt    = (bf16*)alloc((size_t)128 * 2944 * 2);
  bf16*  Btf1    = (bf16*)alloc((size_t)1024 * 256 * 2);
  bf16*  Btf2    = (bf16*)alloc((size_t)128 * 1024 * 2);

  // staging lives inside nb2 (dead until cast_scale runs)
  int* ssrc = (int*)nb2;
  int* sdst = ssrc + (size_t)NBUCK * CAPB;

  bf16* xb  = nb2;   // [N,80]
  bf16* h   = nb2;   // h1 [N,80], h2 [N,160]
  bf16* ag  = nb1;   // agg buffers [N,80] / [N,160]
  bf16* c2  = nb1;   // [B,78,64] (over ag, dead after gcn3_segmax)
  bf16* c3  = nb2;   // [B,23,128] flat [B,2944] (over h, dead after gcn3)
  bf16* f1b = g1b;

  // ---- weight prep + bucket cursor init (single launch) ----
  wprep_all_kernel<<<(WPREP_TOTAL + 255) / 256, 256, 0, stream>>>(
      k2, k3, W1, W2, W3, Wg1, Wg2, Wxt, Wf1, Wf2, Wr2, Wr3, Btw1, Btw2, BtW3,
      Btg1, Btg2, Btxt, Btf1, Btf2, gcur);

  // ---- CSR build (two-level multisplit) ----
  multisplit_kernel<<<NBUCK, 256, 0, stream>>>(ei, gcur, ssrc, sdst);
  bucket_build_kernel<<<NBUCK, 256, 0, stream>>>(ssrc, sdst, gcur, csr,
                                                 rowstart, indeg, dinv);

  // ---- GCN layers (aggregate-first; dinv folded into stored features) ----
  cast_scale_kernel<<<N_NODES * 10 / 256, 256, 0, stream>>>(x, dinv, xb);
  agg80_kernel<<<N_NODES / 4, 256, 0, stream>>>(xb, dinv, rowstart, indeg, csr, ag);
  gemm_mfma_kernel<5, bf16><<<dim3(N_NODES / 64, 1), 256, 0, stream>>>(
      ag, Btw1, b1, dinv, h, N_NODES, 78, 80, 3, 80, 96, 80, 0, 1);
  agg80_kernel<<<N_NODES / 4, 256, 0, stream>>>(h, dinv, rowstart, indeg, csr, ag);
  gemm_mfma_kernel<5, bf16><<<dim3(N_NODES / 64, 2), 256, 0, stream>>>(
      ag, Btw2, b2, dinv, h, N_NODES, 156, 160, 3, 80, 96, 160, 0, 1);
  agg160_kernel<<<N_NODES / 4, 256, 0, stream>>>(h, dinv, rowstart, indeg, csr, ag);
  gcn3_segmax_mfma_kernel<<<NB / 4, 256, 0, stream>>>(ag, BtW3, b3, gb);

  // ---- graph head (MFMA) ----
  gemm_mfma_kernel<4, bf16><<<dim3(NB / 64, 16), 256, 0, stream>>>(
      gb, Btg1, bg1, nullptr, g1b, NB, 1024, 1024, 10, 320, 320, 1024, 0, 1);
  gemm_mfma_kernel<4, bf16><<<dim3(NB / 64, 2), 256, 0, stream>>>(
      g1b, Btg2, bg2, nullptr, gtb, NB, 128, 128, 32, 1024, 1024, 256, 0, 0);

  // ---- conv tower (conv1 fused into convA; pos-major, MFMA) ----
  conv12_kernel<<<NB, 256, 0, stream>>>(xo, k1, kb1, Wr2, kb2, c2);
  convmfma_kernel<64, 78, 88, 5, 23, 4, 128>
      <<<dim3(NB / 4, 2), 256, 0, stream>>>(c2, Wr3, kb3, c3);
  gemm_mfma_kernel<4, bf16><<<dim3(NB / 64, 2), 256, 0, stream>>>(
      c3, Btxt, bxt, nullptr, gtb, NB, 128, 128, 92, 2944, 2944, 256, 128, 0);

  // ---- fused head (MFMA) ----
  gemm_mfma_kernel<4, bf16><<<dim3(NB / 64, 16), 256, 0, stream>>>(
      gtb, Btf1, bf1, nullptr, f1b, NB, 1024, 1024, 8, 256, 256, 1024, 0, 1);
  gemm_mfma_kernel<4, float><<<dim3(NB / 64, 2), 256, 0, stream>>>(
      f1b, Btf2, bf2, nullptr, f2, NB, 128, 128, 32, 1024, 1024, 128, 0, 1);
  final_kernel<<<NB * 64 / 256, 256, 0, stream>>>(f2, Wo, bo, out);
}

// Round 7
// 993.908 us; speedup vs baseline: 1.3113x; 1.0372x over previous
//
#include <hip/hip_runtime.h>
#include <hip/hip_bf16.h>

#define N_NODES 163840
#define N_EDGES 2621440
#define NB      4096
#define NBUCK   320
#define BNODES  512
#define CAPB    9216

typedef __hip_bfloat16 bf16;
typedef __attribute__((ext_vector_type(8))) short short8;
typedef __attribute__((ext_vector_type(4))) float floatx4;

__device__ inline float s2f(short s) {
  union { unsigned u; float f; } cv;
  cv.u = ((unsigned)(unsigned short)s) << 16;
  return cv.f;
}
__device__ inline short f2s(float f) {
  bf16 b = __float2bfloat16(f);
  return *(short*)&b;
}

// ======================= graph preprocessing (multisplit CSR) =======================
// Level 1: split edges into 320 buckets of 512 nodes. Near-full-line writes, no
// cross-XCD sharing of hot lines (fixes 14x WRITE amplification of naive scatter).
__global__ __launch_bounds__(256) void multisplit_kernel(
    const int* __restrict__ ei, int* __restrict__ gcur,
    int* __restrict__ ssrc, int* __restrict__ sdst) {
  __shared__ int hist[NBUCK];
  __shared__ int gbase[NBUCK];
  int tid = threadIdx.x;
  int base = blockIdx.x * 8192;
  for (int i = tid; i < NBUCK; i += 256) hist[i] = 0;
  __syncthreads();
  for (int r = 0; r < 32; r++) {
    int d = ei[N_EDGES + base + r * 256 + tid];
    atomicAdd(&hist[d >> 9], 1);
  }
  __syncthreads();
  for (int i = tid; i < NBUCK; i += 256) {
    int c = hist[i];
    gbase[i] = c ? atomicAdd(&gcur[i], c) : 0;
    hist[i] = 0;  // reuse as local cursor
  }
  __syncthreads();
  for (int r = 0; r < 32; r++) {
    int e = base + r * 256 + tid;
    int s = ei[e];
    int d = ei[N_EDGES + e];
    int bk = d >> 9;
    int pos = gbase[bk] + atomicAdd(&hist[bk], 1);
    sdst[pos] = d;
    ssrc[pos] = s;
  }
}

// Level 2: one wg per bucket builds rowstart/indeg/dinv + places csr (full lines,
// single XCD). Replaces count+scan1/2/3+scatter.
__global__ __launch_bounds__(256) void bucket_build_kernel(
    const int* __restrict__ ssrc, const int* __restrict__ sdst,
    const int* __restrict__ gcur, int* __restrict__ csr,
    int* __restrict__ rowstart, int* __restrict__ indeg,
    float* __restrict__ dinv) {
  int b = blockIdx.x;
  int lo = b * BNODES;
  int base = b * CAPB;
  int size = gcur[b] - base;
  __shared__ int hist[BNODES];
  __shared__ int part[128];
  int tid = threadIdx.x;
  for (int i = tid; i < BNODES; i += 256) hist[i] = 0;
  __syncthreads();
  for (int i = tid; i < size; i += 256)
    atomicAdd(&hist[sdst[base + i] - lo], 1);
  __syncthreads();
  int cnt4[4];
  if (tid < 128) {
    int s = 0;
    for (int j = 0; j < 4; j++) { cnt4[j] = hist[tid * 4 + j]; s += cnt4[j]; }
    part[tid] = s;
  }
  __syncthreads();
  for (int off = 1; off < 128; off <<= 1) {
    int v = 0;
    if (tid >= off && tid < 128) v = part[tid - off];
    __syncthreads();
    if (tid < 128) part[tid] += v;
    __syncthreads();
  }
  if (tid < 128) {
    int run = (tid == 0) ? 0 : part[tid - 1];
    for (int j = 0; j < 4; j++) {
      int i = tid * 4 + j;
      int c = cnt4[j];
      hist[i] = run;
      rowstart[lo + i] = base + run;
      indeg[lo + i] = c;
      dinv[lo + i] = rsqrtf((float)c + 1.0f);
      run += c;
    }
  }
  __syncthreads();
  for (int i = tid; i < size; i += 256) {
    int d = sdst[base + i];
    int pos = base + atomicAdd(&hist[d - lo], 1);
    csr[pos] = ssrc[base + i];
  }
}

// xb[n, 0:78] = x[n,:] * dinv[n]; cols 78..79 = 0  (padded [N,80], short8 stores)
__global__ __launch_bounds__(256) void cast_scale_kernel(const float* __restrict__ x,
                                                         const float* __restrict__ dinv,
                                                         bf16* __restrict__ xb) {
  int i = blockIdx.x * 256 + threadIdx.x;   // chunk id over N*10
  int n = i / 10, c = (i - n * 10) * 8;
  float dn = dinv[n];
  short8 pk;
#pragma unroll
  for (int j = 0; j < 8; j++) {
    int f = c + j;
    float v = (f < 78) ? x[(size_t)n * 78 + f] * dn : 0.f;
    pk[j] = f2s(v);
  }
  *(short8*)((short*)xb + (size_t)n * 80 + c) = pk;
}

// ======================= GCN aggregation (lean gather: 36 VGPR, 0 LDS) ============
// LAW (R2/R5 twice-confirmed): never attach MFMA/LDS compute to these kernels —
// they live on ~22 waves/CU of latency hiding and run at the ~3.8 TB/s random-64B
// service ceiling. Bytes cannot be bought with occupancy.

// F=80 (160 B rows, 10 chunks): 6 lane-groups x 10 chunks (lanes 60-63 idle).
__global__ __launch_bounds__(256) void agg80_kernel(const bf16* __restrict__ hs,
                                                    const float* __restrict__ dinv,
                                                    const int* __restrict__ rowstart,
                                                    const int* __restrict__ indeg,
                                                    const int* __restrict__ csr,
                                                    bf16* __restrict__ out) {
  int node = blockIdx.x * 4 + (threadIdx.x >> 6);
  int lane = threadIdx.x & 63;
  int grp = lane / 10;          // 0..5 active, 6 idle
  int sub = lane - grp * 10;    // 0..9
  bool active = grp < 6;
  int st = rowstart[node];
  int deg = indeg[node];
  int en = st + deg;
  int cnt = deg + 1;            // edges + self
  float dn = dinv[node];
  int pre = (st + lane < en) ? csr[st + lane] : 0;
  float acc[8];
#pragma unroll
  for (int j = 0; j < 8; j++) acc[j] = 0.f;
  for (int e = 0; e < cnt; e += 6) {
    int ri = e + grp;
    bool valid = active && (ri < cnt);
    int idx = __shfl(pre, ri);
    if (ri >= 64) {
      int cidx = st + ri;
      cidx = (cidx < en) ? cidx : st;
      idx = csr[cidx];
    }
    int row = (active && ri < cnt - 1) ? idx : node;
    const short* rp = (const short*)hs + (size_t)row * 80 + sub * 8;
    short8 d = *(const short8*)rp;
    float m = valid ? 1.f : 0.f;
#pragma unroll
    for (int j = 0; j < 8; j++) acc[j] += m * s2f(d[j]);
  }
  short ob[8];
#pragma unroll
  for (int j = 0; j < 8; j++) {
    float v = acc[j];
    float t = 0.f;
#pragma unroll
    for (int g = 0; g < 6; g++) t += __shfl(v, sub + 10 * g);
    ob[j] = f2s(t * dn);
  }
  if (grp == 0) {
    short8 pk;
#pragma unroll
    for (int j = 0; j < 8; j++) pk[j] = ob[j];
    *(short8*)((short*)out + (size_t)node * 80 + sub * 8) = pk;
  }
}

// F=160 gather (320 B rows = 5 aligned 64B lines), writes 160-wide.
__global__ __launch_bounds__(256) void agg160_kernel(const bf16* __restrict__ hs,
                                                     const float* __restrict__ dinv,
                                                     const int* __restrict__ rowstart,
                                                     const int* __restrict__ indeg,
                                                     const int* __restrict__ csr,
                                                     bf16* __restrict__ out) {
  int node = blockIdx.x * 4 + (threadIdx.x >> 6);
  int lane = threadIdx.x & 63;
  int grp = lane >> 3;          // 0..7
  int sub = lane & 7;           // 0..7
  int st = rowstart[node];
  int deg = indeg[node];
  int en = st + deg;
  int cnt = deg + 1;
  float dn = dinv[node];
  int pre = (st + lane < en) ? csr[st + lane] : 0;
  float acc0[8], acc1[8], acc2[8];
#pragma unroll
  for (int j = 0; j < 8; j++) { acc0[j] = 0.f; acc1[j] = 0.f; acc2[j] = 0.f; }
  for (int e = 0; e < cnt; e += 8) {
    int ri = e + grp;
    bool valid = ri < cnt;
    int idx = __shfl(pre, ri);
    if (ri >= 64) {
      int cidx = st + ri;
      cidx = (cidx < en) ? cidx : st;
      idx = csr[cidx];
    }
    int row = (ri < cnt - 1) ? idx : node;
    const short* rp = (const short*)hs + (size_t)row * 160 + sub * 8;
    short8 d0 = *(const short8*)rp;
    short8 d1 = *(const short8*)(rp + 64);
    short8 d2 = *(const short8*)(rp + (sub < 4 ? 128 : 0));
    float m = valid ? 1.f : 0.f;
    float m2 = (valid && sub < 4) ? 1.f : 0.f;
#pragma unroll
    for (int j = 0; j < 8; j++) {
      acc0[j] += m * s2f(d0[j]);
      acc1[j] += m * s2f(d1[j]);
      acc2[j] += m2 * s2f(d2[j]);
    }
  }
  {
    short8 pk;
#pragma unroll
    for (int j = 0; j < 8; j++) {
      float v = acc0[j];
      v += __shfl_xor(v, 8); v += __shfl_xor(v, 16); v += __shfl_xor(v, 32);
      pk[j] = f2s(v * dn);
    }
    if (grp == 0) *(short8*)((short*)out + (size_t)node * 160 + sub * 8) = pk;
  }
  {
    short8 pk;
#pragma unroll
    for (int j = 0; j < 8; j++) {
      float v = acc1[j];
      v += __shfl_xor(v, 8); v += __shfl_xor(v, 16); v += __shfl_xor(v, 32);
      pk[j] = f2s(v * dn);
    }
    if (grp == 0) *(short8*)((short*)out + (size_t)node * 160 + 64 + sub * 8) = pk;
  }
  {
    short8 pk;
#pragma unroll
    for (int j = 0; j < 8; j++) {
      float v = acc2[j];
      v += __shfl_xor(v, 8); v += __shfl_xor(v, 16); v += __shfl_xor(v, 32);
      pk[j] = f2s(v * dn);
    }
    if (grp == 0 && sub < 4)
      *(short8*)((short*)out + (size_t)node * 160 + 128 + sub * 8) = pk;
  }
}

// ======================= MFMA GEMM body (LDS-staged vectorized C store) ============
// bf16 path: stage each wave's 16 x (NT*16) C tile in a per-wave LDS region (wave-
// internal write->read, no barrier — same pattern as conv12's stg), then write out
// short8 16B/lane coalesced. Replaces 4*NT scalar 2-byte stores per thread
// (measured: gemm_l2 ~68us for 78 MB of traffic — store-instruction bound).
template <int NT, typename TC>
__device__ inline void gemm_body(int bx, int by,
    const bf16* __restrict__ A, const bf16* __restrict__ Bt,
    const float* __restrict__ bias, const float* __restrict__ rowScale,
    TC* __restrict__ C, int M, int Nc, int ncstore, int Ksteps, int lda,
    int kpad, int ldc, int coff, int doRelu, bf16* stg_all) {
  constexpr int NTC = NT * 16;
  constexpr int SROW = NTC + 8;
  int tid = threadIdx.x;
  int w = tid >> 6, lane = tid & 63;
  int quad = lane >> 4, l16 = lane & 15;
  int r0 = bx * 64 + w * 16;
  int c0 = by * NTC;
  floatx4 acc[NT];
#pragma unroll
  for (int t = 0; t < NT; t++) acc[t] = (floatx4){0.f, 0.f, 0.f, 0.f};
  const short* Ap = (const short*)A + (size_t)(r0 + l16) * lda + quad * 8;
  const short* Bp = (const short*)Bt + (size_t)(c0 + l16) * kpad + quad * 8;
  for (int s = 0; s < Ksteps; s++) {
    short8 a = *(const short8*)(Ap + s * 32);
#pragma unroll
    for (int t = 0; t < NT; t++) {
      short8 b = *(const short8*)(Bp + (size_t)t * 16 * kpad + s * 32);
      acc[t] = __builtin_amdgcn_mfma_f32_16x16x32_bf16(a, b, acc[t], 0, 0, 0);
    }
  }
  if constexpr (sizeof(TC) == 2) {
    bf16* stg = stg_all + w * 16 * SROW;
#pragma unroll
    for (int t = 0; t < NT; t++) {
      int c = c0 + t * 16 + l16;
      bool valid = c < Nc;
      float bb = (bias && valid) ? bias[c] : 0.f;
#pragma unroll
      for (int r = 0; r < 4; r++) {
        int row = r0 + quad * 4 + r;
        float v = valid ? acc[t][r] + bb : 0.f;
        if (doRelu) v = fmaxf(v, 0.f);
        if (rowScale) v *= rowScale[row];
        stg[(quad * 4 + r) * SROW + t * 16 + l16] = __float2bfloat16(v);
      }
    }
    constexpr int CH = NTC / 8;
    for (int i = lane; i < 16 * CH; i += 64) {
      int rr = i / CH, cc = (i - rr * CH) * 8;
      if (c0 + cc < ncstore) {
        short8 pk = *(const short8*)&stg[rr * SROW + cc];
        *(short8*)((short*)C + (size_t)(r0 + rr) * ldc + coff + c0 + cc) = pk;
      }
    }
  } else {
#pragma unroll
    for (int t = 0; t < NT; t++) {
      int c = c0 + t * 16 + l16;
      if (c >= ncstore) continue;
      bool valid = c < Nc;
      float bb = (bias && valid) ? bias[c] : 0.f;
#pragma unroll
      for (int r = 0; r < 4; r++) {
        int row = r0 + quad * 4 + r;
        float v = valid ? acc[t][r] + bb : 0.f;
        if (doRelu) v = fmaxf(v, 0.f);
        if (rowScale) v *= rowScale[row];
        C[(size_t)row * ldc + coff + c] = v;
      }
    }
  }
}

template <int NT, typename TC>
__global__ __launch_bounds__(256) void gemm_mfma_kernel(
    const bf16* __restrict__ A, const bf16* __restrict__ Bt,
    const float* __restrict__ bias, const float* __restrict__ rowScale,
    TC* __restrict__ C, int M, int Nc, int ncstore, int Ksteps, int lda,
    int kpad, int ldc, int coff, int doRelu) {
  constexpr int SSZ = (sizeof(TC) == 2) ? 4 * 16 * (NT * 16 + 8) : 8;
  __shared__ __align__(16) bf16 stg[SSZ];
  gemm_body<NT, TC>(blockIdx.x, blockIdx.y, A, Bt, bias, rowScale, C, M, Nc,
                    ncstore, Ksteps, lda, kpad, ldc, coff, doRelu, stg);
}

// ================== merged weight prep (+ bucket cursor init) ==================
__device__ inline void wtrans_one(const float* __restrict__ W, bf16* __restrict__ Bt,
                                  int K, int N, int Kpad, int idx) {
  int n = idx / Kpad, k = idx - n * Kpad;
  float v = (k < K && n < N) ? W[(size_t)k * N + n] : 0.f;
  Bt[idx] = __float2bfloat16(v);
}
template <int CI, int NCO>
__device__ inline void wprep_one(const float* __restrict__ kw, bf16* __restrict__ Wr,
                                 int idx) {
  int co = idx % NCO, k = idx / NCO;
  int dl = k / CI, ci = k % CI;
  Wr[idx] = __float2bfloat16(kw[(co * CI + ci) * 8 + dl]);
}
__global__ __launch_bounds__(256) void wprep_all_kernel(
    const float* k2, const float* k3, const float* W1, const float* W2,
    const float* W3, const float* Wg1, const float* Wg2, const float* Wxt,
    const float* Wf1, const float* Wf2, bf16* Wr2, bf16* Wr3, bf16* Btw1,
    bf16* Btw2, bf16* BtW3, bf16* Btg1, bf16* Btg2, bf16* Btxt, bf16* Btf1,
    bf16* Btf2, int* gcur) {
  int idx = blockIdx.x * 256 + threadIdx.x;
  if (idx < 16384) { wprep_one<32, 64>(k2, Wr2, idx); return; }
  idx -= 16384;
  if (idx < 65536) { wprep_one<64, 128>(k3, Wr3, idx); return; }
  idx -= 65536;
  if (idx < 7680) { wtrans_one(W1, Btw1, 78, 78, 96, idx); return; }
  idx -= 7680;
  if (idx < 15360) { wtrans_one(W2, Btw2, 78, 156, 96, idx); return; }
  idx -= 15360;
  if (idx < 51200) { wtrans_one(W3, BtW3, 156, 312, 160, idx); return; }
  idx -= 51200;
  if (idx < 327680) { wtrans_one(Wg1, Btg1, 312, 1024, 320, idx); return; }
  idx -= 327680;
  if (idx < 131072) { wtrans_one(Wg2, Btg2, 1024, 128, 1024, idx); return; }
  idx -= 131072;
  if (idx < 376832) {  // Wxt permuted transpose
    int o = idx / 2944, k = idx - o * 2944;
    int l = k >> 7, co = k & 127;
    Btxt[idx] = __float2bfloat16(Wxt[((size_t)(co * 23 + l)) * 128 + o]);
    return;
  }
  idx -= 376832;
  if (idx < 262144) { wtrans_one(Wf1, Btf1, 256, 1024, 256, idx); return; }
  idx -= 262144;
  if (idx < 131072) { wtrans_one(Wf2, Btf2, 1024, 128, 1024, idx); return; }
  idx -= 131072;
  if (idx < NBUCK) gcur[idx] = idx * CAPB;
}
#define WPREP_TOTAL (16384 + 65536 + 7680 + 15360 + 51200 + 327680 + 131072 + 376832 + 262144 + 131072 + NBUCK)

// ======= fused layer-3 GCN transform + bias + relu + segment-max (MFMA) =============
__global__ __launch_bounds__(256) void gcn3_segmax_mfma_kernel(
    const bf16* __restrict__ agg2, const bf16* __restrict__ BtW3,
    const float* __restrict__ b3, bf16* __restrict__ g) {
  __shared__ __align__(16) bf16 a_lds[160 * 168];
  int tid = threadIdx.x;
  int w = tid >> 6, lane = tid & 63;
  int quad = lane >> 4, l16 = lane & 15;
  int g0 = blockIdx.x * 4;

  short8 bfrag[5][5];
  const short* Bp = (const short*)BtW3 + (size_t)(w * 80 + l16) * 160 + quad * 8;
#pragma unroll
  for (int nt = 0; nt < 5; nt++)
#pragma unroll
    for (int ks = 0; ks < 5; ks++)
      bfrag[nt][ks] = *(const short8*)(Bp + (size_t)nt * 16 * 160 + ks * 32);

  const bf16* src = agg2 + (size_t)g0 * 40 * 160;
  for (int i = tid; i < 160 * 160 / 8; i += 256) {
    int flat = i * 8;
    int row = flat / 160, k = flat - row * 160;
    *(short8*)&a_lds[row * 168 + k] = *(const short8*)&src[flat];
  }
  __syncthreads();

  float gmax[5][4];
#pragma unroll
  for (int nt = 0; nt < 5; nt++)
#pragma unroll
    for (int gi = 0; gi < 4; gi++) gmax[nt][gi] = -3.0e38f;

#pragma unroll
  for (int mt = 0; mt < 10; mt++) {
    floatx4 acc[5];
#pragma unroll
    for (int nt = 0; nt < 5; nt++) acc[nt] = (floatx4){0.f, 0.f, 0.f, 0.f};
#pragma unroll
    for (int ks = 0; ks < 5; ks++) {
      short8 a = *(const short8*)&a_lds[(16 * mt + l16) * 168 + ks * 32 + quad * 8];
#pragma unroll
      for (int nt = 0; nt < 5; nt++)
        acc[nt] = __builtin_amdgcn_mfma_f32_16x16x32_bf16(a, bfrag[nt][ks], acc[nt], 0, 0, 0);
    }
    int gl = (16 * mt + quad * 4) / 40;
#pragma unroll
    for (int nt = 0; nt < 5; nt++) {
      float m4 = fmaxf(fmaxf(acc[nt][0], acc[nt][1]), fmaxf(acc[nt][2], acc[nt][3]));
#pragma unroll
      for (int gi = 0; gi < 4; gi++)
        if (gl == gi) gmax[nt][gi] = fmaxf(gmax[nt][gi], m4);
    }
  }

#pragma unroll
  for (int nt = 0; nt < 5; nt++) {
#pragma unroll
    for (int gi = 0; gi < 4; gi++) {
      float v = gmax[nt][gi];
      v = fmaxf(v, __shfl_xor(v, 16));
      v = fmaxf(v, __shfl_xor(v, 32));
      gmax[nt][gi] = v;
    }
    int c = w * 80 + nt * 16 + l16;
    float bb = (c < 312) ? b3[c] : 0.f;
    float val = fmaxf(gmax[nt][quad] + bb, 0.f);
    g[(size_t)(g0 + quad) * 320 + c] = __float2bfloat16(val);
  }
}

// =========== fused conv1 + convA body (implicit-GEMM, 3-tile-group pooling) =========
// LDS: lds_in[248*40] bf16 (19840 B) + xin[735] f32 (2944 B) + stg[4][48][16] (6144 B)
#define CONV12_SMEM (248 * 40 * 2 + 2944 + 6144)
__device__ inline void conv12_body(int b, const float* __restrict__ xo,
    const float* __restrict__ k1, const float* __restrict__ kb1,
    const bf16* __restrict__ Wr2, const float* __restrict__ kb2,
    bf16* __restrict__ outp, char* smem) {
  bf16* lds_in = (bf16*)smem;
  float* xin = (float*)(smem + 248 * 40 * 2);
  bf16 (*stg)[48][16] = (bf16 (*)[48][16])(smem + 248 * 40 * 2 + 2944);
  int tid = threadIdx.x;
  for (int i = tid; i < 735; i += 256) xin[i] = xo[(size_t)b * 735 + i];
  int co = tid & 31;
  float wreg[8];
#pragma unroll
  for (int k = 0; k < 8; k++) wreg[k] = k1[co * 8 + k];
  float bs = kb1[co];
  int w = tid >> 6, lane = tid & 63;
  int quad = lane >> 4, l16 = lane & 15;
  int co0 = w * 16;
  short8 bfrag[8];
#pragma unroll
  for (int s = 0; s < 8; s++)
#pragma unroll
    for (int j = 0; j < 8; j++)
      bfrag[s][j] = ((const short*)Wr2)[(s * 32 + quad * 8 + j) * 64 + co0 + l16];
  float biasv = kb2[co0 + l16];
  __syncthreads();  // xin ready
  for (int idx = tid; idx < 242 * 32; idx += 256) {
    int l = idx >> 5;
    int base = l * 3;
    float a0 = bs, a1 = bs, a2 = bs;
#pragma unroll
    for (int k = 0; k < 8; k++) {
      float wv = wreg[k];
      a0 += wv * xin[base + k];
      a1 += wv * xin[base + 1 + k];
      a2 += wv * xin[base + 2 + k];
    }
    lds_in[l * 40 + co] =
        __float2bfloat16(fmaxf(0.f, fmaxf(a0, fmaxf(a1, a2))));
  }
  for (int idx = tid; idx < 6 * 32; idx += 256) {
    int rr = idx >> 5, cc = idx & 31;
    lds_in[(242 + rr) * 40 + cc] = __float2bfloat16(0.f);
  }
  __syncthreads();  // lds_in ready
  for (int t = 0; t < 5; t++) {
#pragma unroll
    for (int s3 = 0; s3 < 3; s3++) {
      int mt = 3 * t + s3;
      floatx4 acc = {0.f, 0.f, 0.f, 0.f};
      int m = mt * 16 + l16;
#pragma unroll
      for (int s = 0; s < 8; s++) {
        short8 a = *(const short8*)&lds_in[(m + s) * 40 + quad * 8];
        acc = __builtin_amdgcn_mfma_f32_16x16x32_bf16(a, bfrag[s], acc, 0, 0, 0);
      }
#pragma unroll
      for (int r = 0; r < 4; r++)
        stg[w][s3 * 16 + quad * 4 + r][l16] = __float2bfloat16(acc[r]);
    }
    // pool 48 rows -> 16 outputs (stg[w] per-wave: no cross-wave barrier needed)
    for (int it = lane; it < 256; it += 64) {
      int lo = it >> 4;
      float v0 = __bfloat162float(stg[w][3 * lo][l16]);
      float v1 = __bfloat162float(stg[w][3 * lo + 1][l16]);
      float v2 = __bfloat162float(stg[w][3 * lo + 2][l16]);
      float v = fmaxf(fmaxf(v0, v1), v2) + biasv;
      int l = t * 16 + lo;
      if (l < 78)
        outp[((size_t)b * 78 + l) * 64 + co0 + l16] =
            __float2bfloat16(fmaxf(v, 0.f));
    }
  }
}

// ========= merged: conv12 (4096 blocks) || g-head gemm1 (1024 blocks), 4:1 ==========
// Both compute-bound MFMA bodies (NOT gathers — law respected). Worst-case LDS
// 28.9 KB -> 5 blocks/CU, fine for MFMA occupancy.
__global__ __launch_bounds__(256) void conv12_g1_kernel(
    const float* __restrict__ xo, const float* __restrict__ k1,
    const float* __restrict__ kb1, const bf16* __restrict__ Wr2,
    const float* __restrict__ kb2, bf16* __restrict__ c2,
    const bf16* __restrict__ gb, const bf16* __restrict__ Btg1,
    const float* __restrict__ bg1, bf16* __restrict__ g1b) {
  __shared__ __align__(16) char smem[CONV12_SMEM];
  int bx = blockIdx.x;
  int g = bx / 5, r = bx - g * 5;
  if (r < 4)
    conv12_body(g * 4 + r, xo, k1, kb1, Wr2, kb2, c2, smem);
  else
    gemm_body<4, bf16>(g & 63, g >> 6, gb, Btg1, bg1, nullptr, g1b, NB, 1024,
                       1024, 10, 320, 320, 1024, 0, 1, (bf16*)smem);
}

// ========= merged: Btxt gemm (128 blocks) || g-head gemm2 (128 blocks), 1:1 =========
// Both plain gemm bodies writing disjoint gtb column halves; fills the GPU where
// xt alone used half the CUs.
__global__ __launch_bounds__(256) void xt_g2_kernel(
    const bf16* __restrict__ c3, const bf16* __restrict__ Btxt,
    const float* __restrict__ bxt, const bf16* __restrict__ g1b,
    const bf16* __restrict__ Btg2, const float* __restrict__ bg2,
    bf16* __restrict__ gtb) {
  __shared__ __align__(16) bf16 stg[4 * 16 * 72];
  int bx = blockIdx.x;
  int g = bx >> 1, r = bx & 1;
  if (r == 0)
    gemm_body<4, bf16>(g & 63, g >> 6, c3, Btxt, bxt, nullptr, gtb, NB, 128,
                       128, 92, 2944, 2944, 256, 128, 0, stg);
  else
    gemm_body<4, bf16>(g & 63, g >> 6, g1b, Btg2, bg2, nullptr, gtb, NB, 128,
                       128, 32, 1024, 1024, 256, 0, 0, stg);
}

// ======================= MFMA implicit-GEMM conv + bias + relu + pool3 ==============
template <int CI, int LIN, int LPAD, int MT, int LOUT, int G, int NCO>
__global__ __launch_bounds__(256) void convmfma_kernel(const bf16* __restrict__ in,
                                                       const bf16* __restrict__ Wr,
                                                       const float* __restrict__ kb,
                                                       bf16* __restrict__ outp) {
  constexpr int KSTEPS = 8 * CI / 32;
  constexpr int CIP = CI + 8;
  __shared__ __align__(16) bf16 lds_in[G * LPAD * CIP];
  __shared__ bf16 stg[4][MT * 16][16];
  int tid = threadIdx.x;
  int w = tid >> 6, lane = tid & 63;
  int quad = lane >> 4, l16 = lane & 15;
  int bg = blockIdx.x;
  int co0 = blockIdx.y * 64 + w * 16;

  short8 bfrag[KSTEPS];
#pragma unroll
  for (int s = 0; s < KSTEPS; s++) {
#pragma unroll
    for (int j = 0; j < 8; j++) {
      int k = s * 32 + quad * 8 + j;
      bfrag[s][j] = ((const short*)Wr)[k * NCO + co0 + l16];
    }
  }

  const bf16* gin = in + (size_t)bg * G * LIN * CI;
  constexpr int NELEM = G * LIN * CI;
  for (int i = tid; i < NELEM / 8; i += 256) {
    int flat = i * 8;
    int g = flat / (LIN * CI);
    int rem = flat - g * (LIN * CI);
    int row = rem / CI, ci = rem - row * CI;
    *(short8*)&lds_in[(g * LPAD + row) * CIP + ci] = *(const short8*)&gin[flat];
  }
  constexpr int PADE = G * (LPAD - LIN) * CIP;
  for (int i = tid; i < PADE / 8; i += 256) {
    int flat = i * 8;
    int g = flat / ((LPAD - LIN) * CIP);
    int rem = flat - g * ((LPAD - LIN) * CIP);
    short8 z = {0, 0, 0, 0, 0, 0, 0, 0};
    *(short8*)&lds_in[(g * LPAD + LIN) * CIP + rem] = z;
  }
  __syncthreads();

  for (int g = 0; g < G; g++) {
    const bf16* base = &lds_in[g * LPAD * CIP];
#pragma unroll
    for (int mt = 0; mt < MT; mt++) {
      floatx4 acc = {0.f, 0.f, 0.f, 0.f};
      int m = mt * 16 + l16;
#pragma unroll
      for (int s = 0; s < KSTEPS; s++) {
        int kg0 = s * 32 + quad * 8;
        int dl = kg0 / CI;
        int ci0 = kg0 % CI;
        short8 a = *(const short8*)&base[(m + dl) * CIP + ci0];
        acc = __builtin_amdgcn_mfma_f32_16x16x32_bf16(a, bfrag[s], acc, 0, 0, 0);
      }
#pragma unroll
      for (int r = 0; r < 4; r++)
        stg[w][mt * 16 + quad * 4 + r][l16] = __float2bfloat16(acc[r]);
    }
    __syncthreads();
    float bias = kb[co0 + l16];
    for (int it = lane; it < LOUT * 16; it += 64) {
      int l = it >> 4;
      float v0 = __bfloat162float(stg[w][3 * l][l16]);
      float v1 = __bfloat162float(stg[w][3 * l + 1][l16]);
      float v2 = __bfloat162float(stg[w][3 * l + 2][l16]);
      float v = fmaxf(fmaxf(v0, v1), v2) + bias;
      outp[((size_t)(bg * G + g) * LOUT + l) * NCO + co0 + l16] =
          __float2bfloat16(fmaxf(v, 0.f));
    }
    __syncthreads();
  }
}

// ======================= final head =======================
__global__ __launch_bounds__(256) void final_kernel(const float* __restrict__ f2,
                                                    const float* __restrict__ Wo,
                                                    const float* __restrict__ bo,
                                                    float* __restrict__ out) {
  int wid = (blockIdx.x * blockDim.x + threadIdx.x) >> 6;
  int lane = threadIdx.x & 63;
  if (wid >= NB) return;
  float s = f2[wid * 128 + lane] * Wo[lane] + f2[wid * 128 + 64 + lane] * Wo[64 + lane];
  for (int o = 32; o > 0; o >>= 1) s += __shfl_down(s, o);
  if (lane == 0) out[wid] = s + bo[0];
}

// ======================= launch =======================
extern "C" void kernel_launch(void* const* d_in, const int* in_sizes, int n_in,
                              void* d_out, int out_size, void* d_ws, size_t ws_size,
                              hipStream_t stream) {
  const float* x   = (const float*)d_in[0];
  const int*   ei  = (const int*)d_in[1];
  const float* xo  = (const float*)d_in[3];
  const float* W1  = (const float*)d_in[4];  const float* b1  = (const float*)d_in[5];
  const float* W2  = (const float*)d_in[6];  const float* b2  = (const float*)d_in[7];
  const float* W3  = (const float*)d_in[8];  const float* b3  = (const float*)d_in[9];
  const float* Wg1 = (const float*)d_in[10]; const float* bg1 = (const float*)d_in[11];
  const float* Wg2 = (const float*)d_in[12]; const float* bg2 = (const float*)d_in[13];
  const float* k1  = (const float*)d_in[14]; const float* kb1 = (const float*)d_in[15];
  const float* k2  = (const float*)d_in[16]; const float* kb2 = (const float*)d_in[17];
  const float* k3  = (const float*)d_in[18]; const float* kb3 = (const float*)d_in[19];
  const float* Wxt = (const float*)d_in[20]; const float* bxt = (const float*)d_in[21];
  const float* Wf1 = (const float*)d_in[22]; const float* bf1 = (const float*)d_in[23];
  const float* Wf2 = (const float*)d_in[24]; const float* bf2 = (const float*)d_in[25];
  const float* Wo  = (const float*)d_in[26]; const float* bo  = (const float*)d_in[27];
  float* out = (float*)d_out;

  char* ws = (char*)d_ws;
  size_t off = 0;
  auto alloc = [&](size_t bytes) -> void* {
    void* p = ws + off;
    off += (bytes + 255) & ~(size_t)255;
    return p;
  };

  int*   indeg   = (int*)alloc((size_t)N_NODES * 4);
  float* dinv    = (float*)alloc((size_t)N_NODES * 4);
  int*   rowstart= (int*)alloc((size_t)N_NODES * 4);
  int*   gcur    = (int*)alloc(NBUCK * 4);
  int*   csr     = (int*)alloc((size_t)NBUCK * CAPB * 4 + 256);
  bf16*  nb1     = (bf16*)alloc((size_t)N_NODES * 160 * 2);
  bf16*  nb2     = (bf16*)alloc((size_t)NB * 7744 * 2);
  bf16*  gb      = (bf16*)alloc((size_t)NB * 320 * 2);
  bf16*  g1b     = (bf16*)alloc((size_t)NB * 1024 * 2);
  bf16*  gtb     = (bf16*)alloc((size_t)NB * 256 * 2);
  float* f2      = (float*)alloc((size_t)NB * 128 * 4);
  bf16*  Wr2     = (bf16*)alloc((size_t)256 * 64 * 2);
  bf16*  Wr3     = (bf16*)alloc((size_t)512 * 128 * 2);
  bf16*  Btw1    = (bf16*)alloc((size_t)80 * 96 * 2);
  bf16*  Btw2    = (bf16*)alloc((size_t)160 * 96 * 2);
  bf16*  BtW3    = (bf16*)alloc((size_t)320 * 160 * 2);
  bf16*  Btg1    = (bf16*)alloc((size_t)1024 * 320 * 2);
  bf16*  Btg2    = (bf16*)alloc((size_t)128 * 1024 * 2);
  bf16*  Btxt    = (bf16*)alloc((size_t)128 * 2944 * 2);
  bf16*  Btf1    = (bf16*)alloc((size_t)1024 * 256 * 2);
  bf16*  Btf2    = (bf16*)alloc((size_t)128 * 1024 * 2);

  // staging lives inside nb2 (dead until cast_scale runs)
  int* ssrc = (int*)nb2;
  int* sdst = ssrc + (size_t)NBUCK * CAPB;

  bf16* xb  = nb2;   // [N,80]
  bf16* h   = nb2;   // h1 [N,80], h2 [N,160]
  bf16* ag  = nb1;   // agg buffers [N,80] / [N,160]
  bf16* c2  = nb1;   // [B,78,64] (over ag, dead after gcn3_segmax)
  bf16* c3  = nb2;   // [B,23,128] flat [B,2944] (over h, dead after agg160)
  bf16* f1b = g1b;

  // ---- weight prep + bucket cursor init (single launch) ----
  wprep_all_kernel<<<(WPREP_TOTAL + 255) / 256, 256, 0, stream>>>(
      k2, k3, W1, W2, W3, Wg1, Wg2, Wxt, Wf1, Wf2, Wr2, Wr3, Btw1, Btw2, BtW3,
      Btg1, Btg2, Btxt, Btf1, Btf2, gcur);

  // ---- CSR build (two-level multisplit) ----
  multisplit_kernel<<<NBUCK, 256, 0, stream>>>(ei, gcur, ssrc, sdst);
  bucket_build_kernel<<<NBUCK, 256, 0, stream>>>(ssrc, sdst, gcur, csr,
                                                 rowstart, indeg, dinv);

  // ---- GCN layers (aggregate-first; dinv folded into stored features) ----
  cast_scale_kernel<<<N_NODES * 10 / 256, 256, 0, stream>>>(x, dinv, xb);
  agg80_kernel<<<N_NODES / 4, 256, 0, stream>>>(xb, dinv, rowstart, indeg, csr, ag);
  gemm_mfma_kernel<5, bf16><<<dim3(N_NODES / 64, 1), 256, 0, stream>>>(
      ag, Btw1, b1, dinv, h, N_NODES, 78, 80, 3, 80, 96, 80, 0, 1);
  agg80_kernel<<<N_NODES / 4, 256, 0, stream>>>(h, dinv, rowstart, indeg, csr, ag);
  gemm_mfma_kernel<5, bf16><<<dim3(N_NODES / 64, 2), 256, 0, stream>>>(
      ag, Btw2, b2, dinv, h, N_NODES, 156, 160, 3, 80, 96, 160, 0, 1);
  agg160_kernel<<<N_NODES / 4, 256, 0, stream>>>(h, dinv, rowstart, indeg, csr, ag);
  gcn3_segmax_mfma_kernel<<<NB / 4, 256, 0, stream>>>(ag, BtW3, b3, gb);

  // ---- conv12 || g-head gemm1 (merged, 4:1 interleave) ----
  conv12_g1_kernel<<<5120, 256, 0, stream>>>(xo, k1, kb1, Wr2, kb2, c2, gb,
                                             Btg1, bg1, g1b);

  // ---- convB ----
  convmfma_kernel<64, 78, 88, 5, 23, 4, 128>
      <<<dim3(NB / 4, 2), 256, 0, stream>>>(c2, Wr3, kb3, c3);

  // ---- Btxt gemm || g-head gemm2 (merged, 1:1) ----
  xt_g2_kernel<<<256, 256, 0, stream>>>(c3, Btxt, bxt, g1b, Btg2, bg2, gtb);

  // ---- fused head (MFMA) ----
  gemm_mfma_kernel<4, bf16><<<dim3(NB / 64, 16), 256, 0, stream>>>(
      gtb, Btf1, bf1, nullptr, f1b, NB, 1024, 1024, 8, 256, 256, 1024, 0, 1);
  gemm_mfma_kernel<4, float><<<dim3(NB / 64, 2), 256, 0, stream>>>(
      f1b, Btf2, bf2, nullptr, f2, NB, 128, 128, 32, 1024, 1024, 128, 0, 1);
  final_kernel<<<NB * 64 / 256, 256, 0, stream>>>(f2, Wo, bo, out);
}